// Round 1
// baseline (526.816 us; speedup 1.0000x reference)
//
#include <hip/hip_runtime.h>
#include <hip/hip_bf16.h>
#include <math.h>

#define NN 50000      // nodes
#define NE 500000     // edges (before self loops)
#define NP 10000      // pairs
#define FIN 128
#define HD 256
#define NE_TOT (NE + NN)   // with self loops

// ---------------- fp32 tiled GEMM: C[M,N] = A[M,K] @ B[K,N], row-major ----------------
// BM=BN=64, BK=16, 256 threads, 4x4 per thread. N,K must be multiples of 64/16.
__global__ __launch_bounds__(256)
void sgemm_kernel(const float* __restrict__ A, const float* __restrict__ B,
                  float* __restrict__ C, int M, int N, int K) {
  __shared__ float As[16][64];
  __shared__ float Bs[16][64];
  const int tid = threadIdx.x;
  const int tx = tid & 15;
  const int ty = tid >> 4;
  const int row0 = blockIdx.x * 64;
  const int col0 = blockIdx.y * 64;
  float acc[4][4] = {};
  for (int k0 = 0; k0 < K; k0 += 16) {
#pragma unroll
    for (int i = 0; i < 4; i++) {
      int r = ty + i * 16;
      int c = tx;
      int gr = row0 + r;
      As[c][r] = (gr < M) ? A[(size_t)gr * K + k0 + c] : 0.f;
    }
#pragma unroll
    for (int i = 0; i < 4; i++) {
      int e = tid + i * 256;
      int r = e >> 6;
      int c = e & 63;
      Bs[r][c] = B[(size_t)(k0 + r) * N + col0 + c];
    }
    __syncthreads();
#pragma unroll
    for (int kk = 0; kk < 16; kk++) {
      float a[4], b[4];
#pragma unroll
      for (int m = 0; m < 4; m++) a[m] = As[kk][ty * 4 + m];
#pragma unroll
      for (int n = 0; n < 4; n++) b[n] = Bs[kk][tx * 4 + n];
#pragma unroll
      for (int m = 0; m < 4; m++)
#pragma unroll
        for (int n = 0; n < 4; n++) acc[m][n] += a[m] * b[n];
    }
    __syncthreads();
  }
#pragma unroll
  for (int m = 0; m < 4; m++) {
    int gr = row0 + ty * 4 + m;
    if (gr >= M) continue;
#pragma unroll
    for (int n = 0; n < 4; n++)
      C[(size_t)gr * N + col0 + tx * 4 + n] = acc[m][n];
  }
}

// ---------------- es/ed = h @ a_s, h @ a_d (one wave per node) ----------------
__global__ void dots_kernel(const float* __restrict__ h, const float* __restrict__ a_s,
                            const float* __restrict__ a_d, float* __restrict__ es,
                            float* __restrict__ ed, int n, int F) {
  int wid = (blockIdx.x * blockDim.x + threadIdx.x) >> 6;
  int lane = threadIdx.x & 63;
  if (wid >= n) return;
  const float* hp = h + (size_t)wid * F;
  float s = 0.f, d = 0.f;
  for (int f = lane; f < F; f += 64) {
    float v = hp[f];
    s += v * a_s[f];
    d += v * a_d[f];
  }
#pragma unroll
  for (int off = 32; off; off >>= 1) {
    s += __shfl_down(s, off);
    d += __shfl_down(d, off);
  }
  if (lane == 0) { es[wid] = s; ed[wid] = d; }
}

// ---------------- CSR build ----------------
__global__ void init_deg_kernel(int* __restrict__ deg, int n) {
  int i = blockIdx.x * blockDim.x + threadIdx.x;
  if (i < n) deg[i] = 1;  // self loop prebaked
}

__global__ void hist_kernel(const int* __restrict__ dst, int E, int* __restrict__ deg) {
  int e = blockIdx.x * blockDim.x + threadIdx.x;
  if (e < E) atomicAdd(&deg[dst[e]], 1);
}

__global__ void scan_phase1(const int* __restrict__ deg, int* __restrict__ incl,
                            int* __restrict__ bsum, int n) {
  __shared__ int tmp[256];
  int i = blockIdx.x * 256 + threadIdx.x;
  int v = (i < n) ? deg[i] : 0;
  tmp[threadIdx.x] = v;
  __syncthreads();
  for (int off = 1; off < 256; off <<= 1) {
    int t = (threadIdx.x >= off) ? tmp[threadIdx.x - off] : 0;
    __syncthreads();
    tmp[threadIdx.x] += t;
    __syncthreads();
  }
  if (i < n) incl[i] = tmp[threadIdx.x];
  if (threadIdx.x == 255) bsum[blockIdx.x] = tmp[255];
}

__global__ void scan_phase2(int* __restrict__ bsum, int nb) {
  __shared__ int tmp[256];
  int v = (threadIdx.x < nb) ? bsum[threadIdx.x] : 0;
  tmp[threadIdx.x] = v;
  __syncthreads();
  for (int off = 1; off < 256; off <<= 1) {
    int t = (threadIdx.x >= off) ? tmp[threadIdx.x - off] : 0;
    __syncthreads();
    tmp[threadIdx.x] += t;
    __syncthreads();
  }
  if (threadIdx.x < nb) bsum[threadIdx.x] = tmp[threadIdx.x] - v;  // exclusive
}

__global__ void scan_phase3(const int* __restrict__ deg, const int* __restrict__ incl,
                            const int* __restrict__ bsum, int* __restrict__ row_ptr,
                            int* __restrict__ cursor, int n, int total) {
  int i = blockIdx.x * 256 + threadIdx.x;
  if (i < n) {
    int excl = incl[i] - deg[i] + bsum[blockIdx.x];
    row_ptr[i] = excl;
    cursor[i] = excl;
  }
  if (i == n) row_ptr[n] = total;
}

__global__ void scatter_kernel(const int* __restrict__ src, const int* __restrict__ dst,
                               int E, int N, int* __restrict__ cursor, int* __restrict__ ssrc) {
  int e = blockIdx.x * blockDim.x + threadIdx.x;
  if (e < E) {
    int pos = atomicAdd(&cursor[dst[e]], 1);
    ssrc[pos] = src[e];
  } else if (e < E + N) {
    int i = e - E;
    int pos = atomicAdd(&cursor[i], 1);
    ssrc[pos] = i;
  }
}

// ---------------- edge softmax (one wave per dst node) ----------------
__global__ void softmax_kernel(const int* __restrict__ row_ptr, const int* __restrict__ ssrc,
                               const float* __restrict__ es, const float* __restrict__ ed,
                               float* __restrict__ alpha, int n) {
  int wid = (blockIdx.x * blockDim.x + threadIdx.x) >> 6;
  int lane = threadIdx.x & 63;
  if (wid >= n) return;
  int s = row_ptr[wid], e = row_ptr[wid + 1];
  float edv = ed[wid];
  float m = -1e30f;
  for (int p = s + lane; p < e; p += 64) {
    float l = es[ssrc[p]] + edv;
    l = (l > 0.f) ? l : 0.2f * l;
    m = fmaxf(m, l);
  }
#pragma unroll
  for (int off = 32; off; off >>= 1) m = fmaxf(m, __shfl_down(m, off));
  m = __shfl(m, 0);
  float sum = 0.f;
  for (int p = s + lane; p < e; p += 64) {
    float l = es[ssrc[p]] + edv;
    l = (l > 0.f) ? l : 0.2f * l;
    float pv = expf(l - m);
    alpha[p] = pv;
    sum += pv;
  }
#pragma unroll
  for (int off = 32; off; off >>= 1) sum += __shfl_down(sum, off);
  sum = __shfl(sum, 0);
  float inv = 1.0f / sum;
  for (int p = s + lane; p < e; p += 64) alpha[p] *= inv;
}

// ---------------- aggregation: out[i][f] = sum_e alpha[e]*h[src[e]][f] + b[f] ----------------
template <int F, bool RELU>
__global__ void aggregate_kernel(const int* __restrict__ row_ptr, const int* __restrict__ ssrc,
                                 const float* __restrict__ alpha, const float* __restrict__ h,
                                 const float* __restrict__ bias, float* __restrict__ out, int n) {
  int i = blockIdx.x;
  int f = threadIdx.x;
  int s = row_ptr[i], e = row_ptr[i + 1];
  float acc = 0.f;
  for (int p = s; p < e; p++) {
    int src = ssrc[p];
    float a = alpha[p];
    acc += a * h[(size_t)src * F + f];
  }
  acc += bias[f];
  if (RELU) acc = fmaxf(acc, 0.f);
  out[(size_t)i * F + f] = acc;
}

// ---------------- link predictor (one wave per pair) ----------------
__global__ void predict_kernel(const float* __restrict__ h2, const int* __restrict__ mask,
                               const float* __restrict__ Wl, const float* __restrict__ bl,
                               float* __restrict__ out, int P, int F) {
  int wid = (blockIdx.x * blockDim.x + threadIdx.x) >> 6;
  int lane = threadIdx.x & 63;
  if (wid >= P) return;
  int m0 = mask[wid * 2 + 0];
  int m1 = mask[wid * 2 + 1];
  float s = 0.f;
  for (int f = lane; f < F; f += 64) {
    s += h2[(size_t)m0 * F + f] * Wl[f];
    s += h2[(size_t)m1 * F + f] * Wl[F + f];
  }
#pragma unroll
  for (int off = 32; off; off >>= 1) s += __shfl_down(s, off);
  if (lane == 0) {
    float z = s + bl[0];
    out[wid] = 1.0f / (1.0f + expf(-z));
  }
}

extern "C" void kernel_launch(void* const* d_in, const int* in_sizes, int n_in,
                              void* d_out, int out_size, void* d_ws, size_t ws_size,
                              hipStream_t stream) {
  const float* features = (const float*)d_in[0];
  const int* edge_index = (const int*)d_in[1];
  const int* mask       = (const int*)d_in[2];
  const float* W1     = (const float*)d_in[3];
  const float* a_src1 = (const float*)d_in[4];
  const float* a_dst1 = (const float*)d_in[5];
  const float* b1     = (const float*)d_in[6];
  const float* W2     = (const float*)d_in[7];
  const float* a_src2 = (const float*)d_in[8];
  const float* a_dst2 = (const float*)d_in[9];
  const float* b2     = (const float*)d_in[10];
  const float* Wl     = (const float*)d_in[11];
  const float* bl     = (const float*)d_in[12];
  float* out = (float*)d_out;

  const int* src = edge_index;        // [E]
  const int* dst = edge_index + NE;   // [E]

  // ---- workspace layout (bytes) ----
  char* ws = (char*)d_ws;
  size_t off = 0;
  auto alloc = [&](size_t bytes) {
    void* p = ws + off;
    off += (bytes + 255) & ~(size_t)255;
    return p;
  };
  float* h_buf   = (float*)alloc((size_t)NN * HD * 4);   // h1, then h2 (N x 128 fits)
  float* x2_buf  = (float*)alloc((size_t)NN * HD * 4);   // relu(out1), then out2
  float* es_buf  = (float*)alloc((size_t)NN * 4);
  float* ed_buf  = (float*)alloc((size_t)NN * 4);
  float* alpha   = (float*)alloc((size_t)NE_TOT * 4);
  int* deg       = (int*)alloc((size_t)NN * 4);
  int* incl      = (int*)alloc((size_t)NN * 4);
  int* bsum      = (int*)alloc(1024);
  int* row_ptr   = (int*)alloc((size_t)(NN + 1) * 4);
  int* cursor    = (int*)alloc((size_t)NN * 4);
  int* ssrc      = (int*)alloc((size_t)NE_TOT * 4);
  (void)ws_size; (void)in_sizes; (void)n_in; (void)out_size;

  const int nblk_n256 = (NN + 255) / 256;          // 196
  const int nblk_wavepn = (NN * 64 + 255) / 256;   // 12500

  // ---- CSR build (shared by both layers) ----
  init_deg_kernel<<<nblk_n256, 256, 0, stream>>>(deg, NN);
  hist_kernel<<<(NE + 255) / 256, 256, 0, stream>>>(dst, NE, deg);
  scan_phase1<<<nblk_n256, 256, 0, stream>>>(deg, incl, bsum, NN);
  scan_phase2<<<1, 256, 0, stream>>>(bsum, nblk_n256);
  scan_phase3<<<nblk_n256 + 1, 256, 0, stream>>>(deg, incl, bsum, row_ptr, cursor, NN, NE_TOT);
  scatter_kernel<<<(NE_TOT + 255) / 256, 256, 0, stream>>>(src, dst, NE, NN, cursor, ssrc);

  // ---- layer 1: h1 = X @ W1  (50000x128 @ 128x256) ----
  {
    dim3 grid((NN + 63) / 64, HD / 64);
    sgemm_kernel<<<grid, 256, 0, stream>>>(features, W1, h_buf, NN, HD, FIN);
  }
  dots_kernel<<<nblk_wavepn, 256, 0, stream>>>(h_buf, a_src1, a_dst1, es_buf, ed_buf, NN, HD);
  softmax_kernel<<<nblk_wavepn, 256, 0, stream>>>(row_ptr, ssrc, es_buf, ed_buf, alpha, NN);
  aggregate_kernel<HD, true><<<NN, HD, 0, stream>>>(row_ptr, ssrc, alpha, h_buf, b1, x2_buf, NN);

  // ---- layer 2: h2 = x2 @ W2  (50000x256 @ 256x128), h2 reuses h_buf ----
  {
    dim3 grid((NN + 63) / 64, FIN / 64);
    sgemm_kernel<<<grid, 256, 0, stream>>>(x2_buf, W2, h_buf, NN, FIN, HD);
  }
  dots_kernel<<<nblk_wavepn, 256, 0, stream>>>(h_buf, a_src2, a_dst2, es_buf, ed_buf, NN, FIN);
  softmax_kernel<<<nblk_wavepn, 256, 0, stream>>>(row_ptr, ssrc, es_buf, ed_buf, alpha, NN);
  // out2 -> x2_buf (x2 no longer needed)
  aggregate_kernel<FIN, false><<<NN, FIN, 0, stream>>>(row_ptr, ssrc, alpha, h_buf, b2, x2_buf, NN);

  // ---- link predictor ----
  predict_kernel<<<(NP * 64 + 255) / 256, 256, 0, stream>>>(x2_buf, mask, Wl, bl, out, NP, FIN);
}

// Round 2
// 427.909 us; speedup vs baseline: 1.2311x; 1.2311x over previous
//
#include <hip/hip_runtime.h>
#include <hip/hip_bf16.h>
#include <math.h>

#define NN 50000      // nodes
#define NE 500000     // edges (before self loops)
#define NP 10000      // pairs
#define FIN 128
#define HD 256
#define NE_TOT (NE + NN)   // with self loops

// ---------------- fp32 tiled GEMM + fused es/ed dot epilogue ----------------
// C[M,N] = A[M,K] @ B[K,N]; also atomicAdd es[r] += C_row . a_s, ed likewise.
// BM=128, BN=64, BK=16, 256 threads, 8x4 micro-tile per thread.
__global__ __launch_bounds__(256)
void sgemm_fused(const float* __restrict__ A, const float* __restrict__ B,
                 float* __restrict__ C, int M, int N, int K,
                 const float* __restrict__ a_s, const float* __restrict__ a_d,
                 float* __restrict__ es, float* __restrict__ ed) {
  __shared__ float As[16][128];   // [k][m]
  __shared__ float Bs[16][64];    // [k][n]
  const int tid = threadIdx.x;
  const int tx = tid & 15;        // n dim
  const int ty = tid >> 4;        // m dim (0..15)
  const int row0 = blockIdx.x * 128;
  const int col0 = blockIdx.y * 64;
  float acc[8][4] = {};
  for (int k0 = 0; k0 < K; k0 += 16) {
    // stage A: 128x16 = 512 float4-chunks, 2 per thread
#pragma unroll
    for (int j = 0; j < 2; j++) {
      int chunk = tid * 2 + j;
      int r = chunk >> 2;
      int c4 = (chunk & 3) * 4;
      int gr = row0 + r;
      float4 v = make_float4(0.f, 0.f, 0.f, 0.f);
      if (gr < M) v = *(const float4*)(A + (size_t)gr * K + k0 + c4);
      As[c4 + 0][r] = v.x;
      As[c4 + 1][r] = v.y;
      As[c4 + 2][r] = v.z;
      As[c4 + 3][r] = v.w;
    }
    // stage B: 16x64 = 256 float4-chunks, 1 per thread
    {
      int r = tid >> 4;
      int c4 = (tid & 15) * 4;
      *(float4*)&Bs[r][c4] = *(const float4*)(B + (size_t)(k0 + r) * N + col0 + c4);
    }
    __syncthreads();
#pragma unroll
    for (int kk = 0; kk < 16; kk++) {
      float4 a0 = *(const float4*)&As[kk][ty * 8];
      float4 a1 = *(const float4*)&As[kk][ty * 8 + 4];
      float4 b4 = *(const float4*)&Bs[kk][tx * 4];
      float av[8] = {a0.x, a0.y, a0.z, a0.w, a1.x, a1.y, a1.z, a1.w};
      float bv[4] = {b4.x, b4.y, b4.z, b4.w};
#pragma unroll
      for (int m = 0; m < 8; m++)
#pragma unroll
        for (int n = 0; n < 4; n++) acc[m][n] += av[m] * bv[n];
    }
    __syncthreads();
  }
  // store C + fused partial dots
  float4 as4 = *(const float4*)(a_s + col0 + tx * 4);
  float4 ad4 = *(const float4*)(a_d + col0 + tx * 4);
#pragma unroll
  for (int m = 0; m < 8; m++) {
    int gr = row0 + ty * 8 + m;
    if (gr < M)
      *(float4*)(C + (size_t)gr * N + col0 + tx * 4) =
          make_float4(acc[m][0], acc[m][1], acc[m][2], acc[m][3]);
    float ps = acc[m][0] * as4.x + acc[m][1] * as4.y + acc[m][2] * as4.z + acc[m][3] * as4.w;
    float pd = acc[m][0] * ad4.x + acc[m][1] * ad4.y + acc[m][2] * ad4.z + acc[m][3] * ad4.w;
#pragma unroll
    for (int off = 8; off; off >>= 1) {
      ps += __shfl_down(ps, off, 16);
      pd += __shfl_down(pd, off, 16);
    }
    if (tx == 0 && gr < M) {
      atomicAdd(&es[gr], ps);
      atomicAdd(&ed[gr], pd);
    }
  }
}

// ---------------- CSR build ----------------
__global__ void init_deg_kernel(int* __restrict__ deg, int n) {
  int i = blockIdx.x * blockDim.x + threadIdx.x;
  if (i < n) deg[i] = 1;  // self loop prebaked
}

__global__ void hist_kernel(const int* __restrict__ dst, int E, int* __restrict__ deg) {
  int e = blockIdx.x * blockDim.x + threadIdx.x;
  if (e < E) atomicAdd(&deg[dst[e]], 1);
}

__global__ void scan_phase1(const int* __restrict__ deg, int* __restrict__ incl,
                            int* __restrict__ bsum, int n) {
  __shared__ int tmp[256];
  int i = blockIdx.x * 256 + threadIdx.x;
  int v = (i < n) ? deg[i] : 0;
  tmp[threadIdx.x] = v;
  __syncthreads();
  for (int off = 1; off < 256; off <<= 1) {
    int t = (threadIdx.x >= off) ? tmp[threadIdx.x - off] : 0;
    __syncthreads();
    tmp[threadIdx.x] += t;
    __syncthreads();
  }
  if (i < n) incl[i] = tmp[threadIdx.x];
  if (threadIdx.x == 255) bsum[blockIdx.x] = tmp[255];
}

__global__ void scan_phase2(int* __restrict__ bsum, int nb) {
  __shared__ int tmp[256];
  int v = (threadIdx.x < nb) ? bsum[threadIdx.x] : 0;
  tmp[threadIdx.x] = v;
  __syncthreads();
  for (int off = 1; off < 256; off <<= 1) {
    int t = (threadIdx.x >= off) ? tmp[threadIdx.x - off] : 0;
    __syncthreads();
    tmp[threadIdx.x] += t;
    __syncthreads();
  }
  if (threadIdx.x < nb) bsum[threadIdx.x] = tmp[threadIdx.x] - v;  // exclusive
}

__global__ void scan_phase3(const int* __restrict__ deg, const int* __restrict__ incl,
                            const int* __restrict__ bsum, int* __restrict__ row_ptr,
                            int* __restrict__ cursor, int n, int total) {
  int i = blockIdx.x * 256 + threadIdx.x;
  if (i < n) {
    int excl = incl[i] - deg[i] + bsum[blockIdx.x];
    row_ptr[i] = excl;
    cursor[i] = excl;
  }
  if (i == n) row_ptr[n] = total;
}

__global__ void scatter_kernel(const int* __restrict__ src, const int* __restrict__ dst,
                               int E, int N, int* __restrict__ cursor, int* __restrict__ ssrc) {
  int e = blockIdx.x * blockDim.x + threadIdx.x;
  if (e < E) {
    int pos = atomicAdd(&cursor[dst[e]], 1);
    ssrc[pos] = src[e];
  } else if (e < E + N) {
    int i = e - E;
    int pos = atomicAdd(&cursor[i], 1);
    ssrc[pos] = i;
  }
}

// ---------------- edge softmax (one wave per dst node) ----------------
__global__ void softmax_kernel(const int* __restrict__ row_ptr, const int* __restrict__ ssrc,
                               const float* __restrict__ es, const float* __restrict__ ed,
                               float* __restrict__ alpha, int n) {
  int wid = (blockIdx.x * blockDim.x + threadIdx.x) >> 6;
  int lane = threadIdx.x & 63;
  if (wid >= n) return;
  int s = row_ptr[wid], e = row_ptr[wid + 1];
  float edv = ed[wid];
  float m = -1e30f;
  for (int p = s + lane; p < e; p += 64) {
    float l = es[ssrc[p]] + edv;
    l = (l > 0.f) ? l : 0.2f * l;
    m = fmaxf(m, l);
  }
#pragma unroll
  for (int off = 32; off; off >>= 1) m = fmaxf(m, __shfl_down(m, off));
  m = __shfl(m, 0);
  float sum = 0.f;
  for (int p = s + lane; p < e; p += 64) {
    float l = es[ssrc[p]] + edv;
    l = (l > 0.f) ? l : 0.2f * l;
    float pv = expf(l - m);
    alpha[p] = pv;
    sum += pv;
  }
#pragma unroll
  for (int off = 32; off; off >>= 1) sum += __shfl_down(sum, off);
  sum = __shfl(sum, 0);
  float inv = 1.0f / sum;
  for (int p = s + lane; p < e; p += 64) alpha[p] *= inv;
}

// ---------------- aggregation: out[i][:] = sum_e alpha[e]*h[src[e]][:] + b ----------------
// W lanes per node (64 for F=256, 32 for F=128), float4 per lane.
// Lanes cooperatively load edge (src,alpha), shfl-broadcast, 4-edge unroll.
template <int F, bool RELU>
__global__ __launch_bounds__(256)
void aggregate2_kernel(const int* __restrict__ row_ptr, const int* __restrict__ ssrc,
                       const float* __restrict__ alpha, const float* __restrict__ h,
                       const float* __restrict__ bias, float* __restrict__ out, int n) {
  constexpr int W = F / 4;          // lanes per node: 64 (F=256) or 32 (F=128)
  constexpr int NPB = 256 / W;      // nodes per block: 4 or 8
  int i = blockIdx.x * NPB + threadIdx.x / W;
  int ls = threadIdx.x & (W - 1);
  int s = row_ptr[i], e = row_ptr[i + 1];
  const float* hb = h + ls * 4;
  float4 acc0 = {0, 0, 0, 0}, acc1 = {0, 0, 0, 0}, acc2 = {0, 0, 0, 0}, acc3 = {0, 0, 0, 0};
  for (int p0 = s; p0 < e; p0 += W) {
    int p = p0 + ls;
    int msrc = 0;
    float ma = 0.f;
    if (p < e) { msrc = ssrc[p]; ma = alpha[p]; }
    int cnt = min(W, e - p0);
    int j = 0;
    for (; j + 4 <= cnt; j += 4) {
      int s0 = __shfl(msrc, j + 0, W), s1 = __shfl(msrc, j + 1, W);
      int s2 = __shfl(msrc, j + 2, W), s3 = __shfl(msrc, j + 3, W);
      float a0 = __shfl(ma, j + 0, W), a1 = __shfl(ma, j + 1, W);
      float a2 = __shfl(ma, j + 2, W), a3 = __shfl(ma, j + 3, W);
      float4 h0 = *(const float4*)(hb + (size_t)s0 * F);
      float4 h1 = *(const float4*)(hb + (size_t)s1 * F);
      float4 h2 = *(const float4*)(hb + (size_t)s2 * F);
      float4 h3 = *(const float4*)(hb + (size_t)s3 * F);
      acc0.x += a0 * h0.x; acc0.y += a0 * h0.y; acc0.z += a0 * h0.z; acc0.w += a0 * h0.w;
      acc1.x += a1 * h1.x; acc1.y += a1 * h1.y; acc1.z += a1 * h1.z; acc1.w += a1 * h1.w;
      acc2.x += a2 * h2.x; acc2.y += a2 * h2.y; acc2.z += a2 * h2.z; acc2.w += a2 * h2.w;
      acc3.x += a3 * h3.x; acc3.y += a3 * h3.y; acc3.z += a3 * h3.z; acc3.w += a3 * h3.w;
    }
    for (; j < cnt; j++) {
      int sj = __shfl(msrc, j, W);
      float aj = __shfl(ma, j, W);
      float4 hv = *(const float4*)(hb + (size_t)sj * F);
      acc0.x += aj * hv.x; acc0.y += aj * hv.y; acc0.z += aj * hv.z; acc0.w += aj * hv.w;
    }
  }
  float4 b4 = *(const float4*)(bias + ls * 4);
  float4 r;
  r.x = acc0.x + acc1.x + acc2.x + acc3.x + b4.x;
  r.y = acc0.y + acc1.y + acc2.y + acc3.y + b4.y;
  r.z = acc0.z + acc1.z + acc2.z + acc3.z + b4.z;
  r.w = acc0.w + acc1.w + acc2.w + acc3.w + b4.w;
  if (RELU) {
    r.x = fmaxf(r.x, 0.f); r.y = fmaxf(r.y, 0.f);
    r.z = fmaxf(r.z, 0.f); r.w = fmaxf(r.w, 0.f);
  }
  *(float4*)(out + (size_t)i * F + ls * 4) = r;
}

// ---------------- link predictor (one wave per pair, float2 per lane) ----------------
__global__ void predict_kernel(const float* __restrict__ h2, const int* __restrict__ mask,
                               const float* __restrict__ Wl, const float* __restrict__ bl,
                               float* __restrict__ out, int P) {
  int wid = (blockIdx.x * blockDim.x + threadIdx.x) >> 6;
  int lane = threadIdx.x & 63;
  if (wid >= P) return;
  int m0 = mask[wid * 2 + 0];
  int m1 = mask[wid * 2 + 1];
  float2 x0 = *(const float2*)(h2 + (size_t)m0 * FIN + lane * 2);
  float2 x1 = *(const float2*)(h2 + (size_t)m1 * FIN + lane * 2);
  float2 w0 = *(const float2*)(Wl + lane * 2);
  float2 w1 = *(const float2*)(Wl + FIN + lane * 2);
  float s = x0.x * w0.x + x0.y * w0.y + x1.x * w1.x + x1.y * w1.y;
#pragma unroll
  for (int off = 32; off; off >>= 1) s += __shfl_down(s, off);
  if (lane == 0) {
    float z = s + bl[0];
    out[wid] = 1.0f / (1.0f + expf(-z));
  }
}

extern "C" void kernel_launch(void* const* d_in, const int* in_sizes, int n_in,
                              void* d_out, int out_size, void* d_ws, size_t ws_size,
                              hipStream_t stream) {
  const float* features = (const float*)d_in[0];
  const int* edge_index = (const int*)d_in[1];
  const int* mask       = (const int*)d_in[2];
  const float* W1     = (const float*)d_in[3];
  const float* a_src1 = (const float*)d_in[4];
  const float* a_dst1 = (const float*)d_in[5];
  const float* b1     = (const float*)d_in[6];
  const float* W2     = (const float*)d_in[7];
  const float* a_src2 = (const float*)d_in[8];
  const float* a_dst2 = (const float*)d_in[9];
  const float* b2     = (const float*)d_in[10];
  const float* Wl     = (const float*)d_in[11];
  const float* bl     = (const float*)d_in[12];
  float* out = (float*)d_out;

  const int* src = edge_index;        // [E]
  const int* dst = edge_index + NE;   // [E]

  // ---- workspace layout ----
  char* ws = (char*)d_ws;
  size_t off = 0;
  auto alloc = [&](size_t bytes) {
    void* p = ws + off;
    off += (bytes + 255) & ~(size_t)255;
    return p;
  };
  float* h_buf   = (float*)alloc((size_t)NN * HD * 4);   // h1, then h2
  float* x2_buf  = (float*)alloc((size_t)NN * HD * 4);   // relu(out1), then out2
  float* es_buf  = (float*)alloc((size_t)NN * 4);
  float* ed_buf  = (float*)alloc((size_t)NN * 4);
  float* alpha   = (float*)alloc((size_t)NE_TOT * 4);
  int* deg       = (int*)alloc((size_t)NN * 4);
  int* incl      = (int*)alloc((size_t)NN * 4);
  int* bsum      = (int*)alloc(1024);
  int* row_ptr   = (int*)alloc((size_t)(NN + 1) * 4);
  int* cursor    = (int*)alloc((size_t)NN * 4);
  int* ssrc      = (int*)alloc((size_t)NE_TOT * 4);
  (void)ws_size; (void)in_sizes; (void)n_in; (void)out_size;

  const int nblk_n256 = (NN + 255) / 256;          // 196
  const int nblk_wavepn = (NN * 64 + 255) / 256;   // 12500

  // ---- CSR build ----
  init_deg_kernel<<<nblk_n256, 256, 0, stream>>>(deg, NN);
  hist_kernel<<<(NE + 255) / 256, 256, 0, stream>>>(dst, NE, deg);
  scan_phase1<<<nblk_n256, 256, 0, stream>>>(deg, incl, bsum, NN);
  scan_phase2<<<1, 256, 0, stream>>>(bsum, nblk_n256);
  scan_phase3<<<nblk_n256 + 1, 256, 0, stream>>>(deg, incl, bsum, row_ptr, cursor, NN, NE_TOT);
  scatter_kernel<<<(NE_TOT + 255) / 256, 256, 0, stream>>>(src, dst, NE, NN, cursor, ssrc);

  // ---- layer 1: h1 = X @ W1 + fused es/ed ----
  hipMemsetAsync(es_buf, 0, (size_t)NN * 4, stream);
  hipMemsetAsync(ed_buf, 0, (size_t)NN * 4, stream);
  {
    dim3 grid((NN + 127) / 128, HD / 64);
    sgemm_fused<<<grid, 256, 0, stream>>>(features, W1, h_buf, NN, HD, FIN,
                                          a_src1, a_dst1, es_buf, ed_buf);
  }
  softmax_kernel<<<nblk_wavepn, 256, 0, stream>>>(row_ptr, ssrc, es_buf, ed_buf, alpha, NN);
  aggregate2_kernel<HD, true><<<NN / 4, 256, 0, stream>>>(row_ptr, ssrc, alpha, h_buf, b1, x2_buf, NN);

  // ---- layer 2: h2 = x2 @ W2 + fused es/ed ----
  hipMemsetAsync(es_buf, 0, (size_t)NN * 4, stream);
  hipMemsetAsync(ed_buf, 0, (size_t)NN * 4, stream);
  {
    dim3 grid((NN + 127) / 128, FIN / 64);
    sgemm_fused<<<grid, 256, 0, stream>>>(x2_buf, W2, h_buf, NN, FIN, HD,
                                          a_src2, a_dst2, es_buf, ed_buf);
  }
  softmax_kernel<<<nblk_wavepn, 256, 0, stream>>>(row_ptr, ssrc, es_buf, ed_buf, alpha, NN);
  aggregate2_kernel<FIN, false><<<NN / 8, 256, 0, stream>>>(row_ptr, ssrc, alpha, h_buf, b2, x2_buf, NN);

  // ---- link predictor ----
  predict_kernel<<<(NP * 64 + 255) / 256, 256, 0, stream>>>(x2_buf, mask, Wl, bl, out, NP);
}

// Round 3
// 381.741 us; speedup vs baseline: 1.3800x; 1.1209x over previous
//
#include <hip/hip_runtime.h>
#include <hip/hip_bf16.h>
#include <math.h>

#define NN 50000      // nodes
#define NE 500000     // edges (before self loops)
#define NP 10000      // pairs
#define FIN 128
#define HD 256
#define NE_TOT (NE + NN)   // with self loops

// round-to-nearest-even fp32 -> bf16 bits
__device__ inline unsigned short f2bf(float f) {
  unsigned int u = __float_as_uint(f);
  unsigned int r = (u + 0x7fffu + ((u >> 16) & 1u)) >> 16;
  return (unsigned short)r;
}

// unpack 4 consecutive bf16 (as uint2) -> float4
__device__ inline float4 bf16x4_to_float4(uint2 u) {
  float4 r;
  r.x = __uint_as_float(u.x << 16);
  r.y = __uint_as_float(u.x & 0xffff0000u);
  r.z = __uint_as_float(u.y << 16);
  r.w = __uint_as_float(u.y & 0xffff0000u);
  return r;
}

// ---------------- fp32 tiled GEMM + fused es/ed dot epilogue, bf16 C output ----------------
// C[M,N](bf16) = A[M,K] @ B[K,N]; also atomicAdd es[r] += C_row . a_s, ed likewise (fp32).
// BM=128, BN=64, BK=16, 256 threads, 8x4 micro-tile per thread.
__global__ __launch_bounds__(256)
void sgemm_fused(const float* __restrict__ A, const float* __restrict__ B,
                 unsigned short* __restrict__ C, int M, int N, int K,
                 const float* __restrict__ a_s, const float* __restrict__ a_d,
                 float* __restrict__ es, float* __restrict__ ed) {
  __shared__ float As[16][128];   // [k][m]
  __shared__ float Bs[16][64];    // [k][n]
  const int tid = threadIdx.x;
  const int tx = tid & 15;        // n dim
  const int ty = tid >> 4;        // m dim (0..15)
  const int row0 = blockIdx.x * 128;
  const int col0 = blockIdx.y * 64;
  float acc[8][4] = {};
  for (int k0 = 0; k0 < K; k0 += 16) {
#pragma unroll
    for (int j = 0; j < 2; j++) {
      int chunk = tid * 2 + j;
      int r = chunk >> 2;
      int c4 = (chunk & 3) * 4;
      int gr = row0 + r;
      float4 v = make_float4(0.f, 0.f, 0.f, 0.f);
      if (gr < M) v = *(const float4*)(A + (size_t)gr * K + k0 + c4);
      As[c4 + 0][r] = v.x;
      As[c4 + 1][r] = v.y;
      As[c4 + 2][r] = v.z;
      As[c4 + 3][r] = v.w;
    }
    {
      int r = tid >> 4;
      int c4 = (tid & 15) * 4;
      *(float4*)&Bs[r][c4] = *(const float4*)(B + (size_t)(k0 + r) * N + col0 + c4);
    }
    __syncthreads();
#pragma unroll
    for (int kk = 0; kk < 16; kk++) {
      float4 a0 = *(const float4*)&As[kk][ty * 8];
      float4 a1 = *(const float4*)&As[kk][ty * 8 + 4];
      float4 b4 = *(const float4*)&Bs[kk][tx * 4];
      float av[8] = {a0.x, a0.y, a0.z, a0.w, a1.x, a1.y, a1.z, a1.w};
      float bv[4] = {b4.x, b4.y, b4.z, b4.w};
#pragma unroll
      for (int m = 0; m < 8; m++)
#pragma unroll
        for (int n = 0; n < 4; n++) acc[m][n] += av[m] * bv[n];
    }
    __syncthreads();
  }
  float4 as4 = *(const float4*)(a_s + col0 + tx * 4);
  float4 ad4 = *(const float4*)(a_d + col0 + tx * 4);
#pragma unroll
  for (int m = 0; m < 8; m++) {
    int gr = row0 + ty * 8 + m;
    if (gr < M) {
      uint2 pk;
      pk.x = (unsigned int)f2bf(acc[m][0]) | ((unsigned int)f2bf(acc[m][1]) << 16);
      pk.y = (unsigned int)f2bf(acc[m][2]) | ((unsigned int)f2bf(acc[m][3]) << 16);
      *(uint2*)(C + (size_t)gr * N + col0 + tx * 4) = pk;
    }
    float ps = acc[m][0] * as4.x + acc[m][1] * as4.y + acc[m][2] * as4.z + acc[m][3] * as4.w;
    float pd = acc[m][0] * ad4.x + acc[m][1] * ad4.y + acc[m][2] * ad4.z + acc[m][3] * ad4.w;
#pragma unroll
    for (int off = 8; off; off >>= 1) {
      ps += __shfl_down(ps, off, 16);
      pd += __shfl_down(pd, off, 16);
    }
    if (tx == 0 && gr < M) {
      atomicAdd(&es[gr], ps);
      atomicAdd(&ed[gr], pd);
    }
  }
}

// ---------------- CSR build ----------------
__global__ void init_deg_kernel(int* __restrict__ deg, int n) {
  int i = blockIdx.x * blockDim.x + threadIdx.x;
  if (i < n) deg[i] = 1;  // self loop prebaked
}

__global__ void hist_kernel(const int* __restrict__ dst, int E, int* __restrict__ deg) {
  int e = blockIdx.x * blockDim.x + threadIdx.x;
  if (e < E) atomicAdd(&deg[dst[e]], 1);
}

__global__ void scan_phase1(const int* __restrict__ deg, int* __restrict__ incl,
                            int* __restrict__ bsum, int n) {
  __shared__ int tmp[256];
  int i = blockIdx.x * 256 + threadIdx.x;
  int v = (i < n) ? deg[i] : 0;
  tmp[threadIdx.x] = v;
  __syncthreads();
  for (int off = 1; off < 256; off <<= 1) {
    int t = (threadIdx.x >= off) ? tmp[threadIdx.x - off] : 0;
    __syncthreads();
    tmp[threadIdx.x] += t;
    __syncthreads();
  }
  if (i < n) incl[i] = tmp[threadIdx.x];
  if (threadIdx.x == 255) bsum[blockIdx.x] = tmp[255];
}

__global__ void scan_phase2(int* __restrict__ bsum, int nb) {
  __shared__ int tmp[256];
  int v = (threadIdx.x < nb) ? bsum[threadIdx.x] : 0;
  tmp[threadIdx.x] = v;
  __syncthreads();
  for (int off = 1; off < 256; off <<= 1) {
    int t = (threadIdx.x >= off) ? tmp[threadIdx.x - off] : 0;
    __syncthreads();
    tmp[threadIdx.x] += t;
    __syncthreads();
  }
  if (threadIdx.x < nb) bsum[threadIdx.x] = tmp[threadIdx.x] - v;  // exclusive
}

__global__ void scan_phase3(const int* __restrict__ deg, const int* __restrict__ incl,
                            const int* __restrict__ bsum, int* __restrict__ row_ptr,
                            int* __restrict__ cursor, int n, int total) {
  int i = blockIdx.x * 256 + threadIdx.x;
  if (i < n) {
    int excl = incl[i] - deg[i] + bsum[blockIdx.x];
    row_ptr[i] = excl;
    cursor[i] = excl;
  }
  if (i == n) row_ptr[n] = total;
}

__global__ void scatter_kernel(const int* __restrict__ src, const int* __restrict__ dst,
                               int E, int N, int* __restrict__ cursor, int* __restrict__ ssrc) {
  int e = blockIdx.x * blockDim.x + threadIdx.x;
  if (e < E) {
    int pos = atomicAdd(&cursor[dst[e]], 1);
    ssrc[pos] = src[e];
  } else if (e < E + N) {
    int i = e - E;
    int pos = atomicAdd(&cursor[i], 1);
    ssrc[pos] = i;
  }
}

// ---------------- edge softmax (one wave per dst node), unnormalized p + denom ----------------
__global__ void softmax_kernel(const int* __restrict__ row_ptr, const int* __restrict__ ssrc,
                               const float* __restrict__ es, const float* __restrict__ ed,
                               float* __restrict__ alpha, float* __restrict__ denom, int n) {
  int wid = (blockIdx.x * blockDim.x + threadIdx.x) >> 6;
  int lane = threadIdx.x & 63;
  if (wid >= n) return;
  int s = row_ptr[wid], e = row_ptr[wid + 1];
  float edv = ed[wid];
  float m = -1e30f;
  for (int p = s + lane; p < e; p += 64) {
    float l = es[ssrc[p]] + edv;
    l = (l > 0.f) ? l : 0.2f * l;
    m = fmaxf(m, l);
  }
#pragma unroll
  for (int off = 32; off; off >>= 1) m = fmaxf(m, __shfl_down(m, off));
  m = __shfl(m, 0);
  float sum = 0.f;
  for (int p = s + lane; p < e; p += 64) {
    float l = es[ssrc[p]] + edv;
    l = (l > 0.f) ? l : 0.2f * l;
    float pv = expf(l - m);
    alpha[p] = pv;
    sum += pv;
  }
#pragma unroll
  for (int off = 32; off; off >>= 1) sum += __shfl_down(sum, off);
  if (lane == 0) denom[wid] = sum;
}

// ---------------- aggregation: out[i][:] = (sum_e p[e]*h_bf16[src[e]][:]) / denom[i] + b ----------------
// W lanes per node, 4 bf16 (8B) per lane.
template <int F, bool RELU>
__global__ __launch_bounds__(256)
void aggregate_bf16(const int* __restrict__ row_ptr, const int* __restrict__ ssrc,
                    const float* __restrict__ alpha, const float* __restrict__ denom,
                    const unsigned short* __restrict__ h, const float* __restrict__ bias,
                    float* __restrict__ out, int n) {
  constexpr int W = F / 4;          // 64 (F=256) or 32 (F=128)
  constexpr int NPB = 256 / W;
  int i = blockIdx.x * NPB + threadIdx.x / W;
  int ls = threadIdx.x & (W - 1);
  int s = row_ptr[i], e = row_ptr[i + 1];
  const unsigned short* hb = h + ls * 4;
  float4 acc0 = {0, 0, 0, 0}, acc1 = {0, 0, 0, 0}, acc2 = {0, 0, 0, 0}, acc3 = {0, 0, 0, 0};
  for (int p0 = s; p0 < e; p0 += W) {
    int p = p0 + ls;
    int msrc = 0;
    float ma = 0.f;
    if (p < e) { msrc = ssrc[p]; ma = alpha[p]; }
    int cnt = min(W, e - p0);
    int j = 0;
    for (; j + 4 <= cnt; j += 4) {
      int s0 = __shfl(msrc, j + 0, W), s1 = __shfl(msrc, j + 1, W);
      int s2 = __shfl(msrc, j + 2, W), s3 = __shfl(msrc, j + 3, W);
      float a0 = __shfl(ma, j + 0, W), a1 = __shfl(ma, j + 1, W);
      float a2 = __shfl(ma, j + 2, W), a3 = __shfl(ma, j + 3, W);
      float4 h0 = bf16x4_to_float4(*(const uint2*)(hb + (size_t)s0 * F));
      float4 h1 = bf16x4_to_float4(*(const uint2*)(hb + (size_t)s1 * F));
      float4 h2 = bf16x4_to_float4(*(const uint2*)(hb + (size_t)s2 * F));
      float4 h3 = bf16x4_to_float4(*(const uint2*)(hb + (size_t)s3 * F));
      acc0.x += a0 * h0.x; acc0.y += a0 * h0.y; acc0.z += a0 * h0.z; acc0.w += a0 * h0.w;
      acc1.x += a1 * h1.x; acc1.y += a1 * h1.y; acc1.z += a1 * h1.z; acc1.w += a1 * h1.w;
      acc2.x += a2 * h2.x; acc2.y += a2 * h2.y; acc2.z += a2 * h2.z; acc2.w += a2 * h2.w;
      acc3.x += a3 * h3.x; acc3.y += a3 * h3.y; acc3.z += a3 * h3.z; acc3.w += a3 * h3.w;
    }
    for (; j < cnt; j++) {
      int sj = __shfl(msrc, j, W);
      float aj = __shfl(ma, j, W);
      float4 hv = bf16x4_to_float4(*(const uint2*)(hb + (size_t)sj * F));
      acc0.x += aj * hv.x; acc0.y += aj * hv.y; acc0.z += aj * hv.z; acc0.w += aj * hv.w;
    }
  }
  float invd = 1.0f / denom[i];
  float4 b4 = *(const float4*)(bias + ls * 4);
  float4 r;
  r.x = (acc0.x + acc1.x + acc2.x + acc3.x) * invd + b4.x;
  r.y = (acc0.y + acc1.y + acc2.y + acc3.y) * invd + b4.y;
  r.z = (acc0.z + acc1.z + acc2.z + acc3.z) * invd + b4.z;
  r.w = (acc0.w + acc1.w + acc2.w + acc3.w) * invd + b4.w;
  if (RELU) {
    r.x = fmaxf(r.x, 0.f); r.y = fmaxf(r.y, 0.f);
    r.z = fmaxf(r.z, 0.f); r.w = fmaxf(r.w, 0.f);
  }
  *(float4*)(out + (size_t)i * F + ls * 4) = r;
}

// ---------------- link predictor (one wave per pair, float2 per lane) ----------------
__global__ void predict_kernel(const float* __restrict__ h2, const int* __restrict__ mask,
                               const float* __restrict__ Wl, const float* __restrict__ bl,
                               float* __restrict__ out, int P) {
  int wid = (blockIdx.x * blockDim.x + threadIdx.x) >> 6;
  int lane = threadIdx.x & 63;
  if (wid >= P) return;
  int m0 = mask[wid * 2 + 0];
  int m1 = mask[wid * 2 + 1];
  float2 x0 = *(const float2*)(h2 + (size_t)m0 * FIN + lane * 2);
  float2 x1 = *(const float2*)(h2 + (size_t)m1 * FIN + lane * 2);
  float2 w0 = *(const float2*)(Wl + lane * 2);
  float2 w1 = *(const float2*)(Wl + FIN + lane * 2);
  float s = x0.x * w0.x + x0.y * w0.y + x1.x * w1.x + x1.y * w1.y;
#pragma unroll
  for (int off = 32; off; off >>= 1) s += __shfl_down(s, off);
  if (lane == 0) {
    float z = s + bl[0];
    out[wid] = 1.0f / (1.0f + expf(-z));
  }
}

extern "C" void kernel_launch(void* const* d_in, const int* in_sizes, int n_in,
                              void* d_out, int out_size, void* d_ws, size_t ws_size,
                              hipStream_t stream) {
  const float* features = (const float*)d_in[0];
  const int* edge_index = (const int*)d_in[1];
  const int* mask       = (const int*)d_in[2];
  const float* W1     = (const float*)d_in[3];
  const float* a_src1 = (const float*)d_in[4];
  const float* a_dst1 = (const float*)d_in[5];
  const float* b1     = (const float*)d_in[6];
  const float* W2     = (const float*)d_in[7];
  const float* a_src2 = (const float*)d_in[8];
  const float* a_dst2 = (const float*)d_in[9];
  const float* b2     = (const float*)d_in[10];
  const float* Wl     = (const float*)d_in[11];
  const float* bl     = (const float*)d_in[12];
  float* out = (float*)d_out;

  const int* src = edge_index;        // [E]
  const int* dst = edge_index + NE;   // [E]

  // ---- workspace layout ----
  char* ws = (char*)d_ws;
  size_t off = 0;
  auto alloc = [&](size_t bytes) {
    void* p = ws + off;
    off += (bytes + 255) & ~(size_t)255;
    return p;
  };
  unsigned short* h_buf = (unsigned short*)alloc((size_t)NN * HD * 2);  // h1/h2 in bf16
  float* x2_buf  = (float*)alloc((size_t)NN * HD * 4);   // relu(out1), then out2
  float* es_buf  = (float*)alloc((size_t)NN * 4);
  float* ed_buf  = (float*)alloc((size_t)NN * 4);
  float* denom   = (float*)alloc((size_t)NN * 4);
  float* alpha   = (float*)alloc((size_t)NE_TOT * 4);
  int* deg       = (int*)alloc((size_t)NN * 4);
  int* incl      = (int*)alloc((size_t)NN * 4);
  int* bsum      = (int*)alloc(1024);
  int* row_ptr   = (int*)alloc((size_t)(NN + 1) * 4);
  int* cursor    = (int*)alloc((size_t)NN * 4);
  int* ssrc      = (int*)alloc((size_t)NE_TOT * 4);
  (void)ws_size; (void)in_sizes; (void)n_in; (void)out_size;

  const int nblk_n256 = (NN + 255) / 256;          // 196
  const int nblk_wavepn = (NN * 64 + 255) / 256;   // 12500

  // ---- CSR build ----
  init_deg_kernel<<<nblk_n256, 256, 0, stream>>>(deg, NN);
  hist_kernel<<<(NE + 255) / 256, 256, 0, stream>>>(dst, NE, deg);
  scan_phase1<<<nblk_n256, 256, 0, stream>>>(deg, incl, bsum, NN);
  scan_phase2<<<1, 256, 0, stream>>>(bsum, nblk_n256);
  scan_phase3<<<nblk_n256 + 1, 256, 0, stream>>>(deg, incl, bsum, row_ptr, cursor, NN, NE_TOT);
  scatter_kernel<<<(NE_TOT + 255) / 256, 256, 0, stream>>>(src, dst, NE, NN, cursor, ssrc);

  // ---- layer 1: h1 = X @ W1 (bf16 out) + fused es/ed ----
  hipMemsetAsync(es_buf, 0, (size_t)NN * 4, stream);
  hipMemsetAsync(ed_buf, 0, (size_t)NN * 4, stream);
  {
    dim3 grid((NN + 127) / 128, HD / 64);
    sgemm_fused<<<grid, 256, 0, stream>>>(features, W1, h_buf, NN, HD, FIN,
                                          a_src1, a_dst1, es_buf, ed_buf);
  }
  softmax_kernel<<<nblk_wavepn, 256, 0, stream>>>(row_ptr, ssrc, es_buf, ed_buf, alpha, denom, NN);
  aggregate_bf16<HD, true><<<NN / 4, 256, 0, stream>>>(row_ptr, ssrc, alpha, denom, h_buf, b1, x2_buf, NN);

  // ---- layer 2: h2 = x2 @ W2 (bf16 out) + fused es/ed ----
  hipMemsetAsync(es_buf, 0, (size_t)NN * 4, stream);
  hipMemsetAsync(ed_buf, 0, (size_t)NN * 4, stream);
  {
    dim3 grid((NN + 127) / 128, FIN / 64);
    sgemm_fused<<<grid, 256, 0, stream>>>(x2_buf, W2, h_buf, NN, FIN, HD,
                                          a_src2, a_dst2, es_buf, ed_buf);
  }
  softmax_kernel<<<nblk_wavepn, 256, 0, stream>>>(row_ptr, ssrc, es_buf, ed_buf, alpha, denom, NN);
  aggregate_bf16<FIN, false><<<NN / 8, 256, 0, stream>>>(row_ptr, ssrc, alpha, denom, h_buf, b2, x2_buf, NN);

  // ---- link predictor ----
  predict_kernel<<<(NP * 64 + 255) / 256, 256, 0, stream>>>(x2_buf, mask, Wl, bl, out, NP);
}

// Round 4
// 293.494 us; speedup vs baseline: 1.7950x; 1.3007x over previous
//
#include <hip/hip_runtime.h>
#include <hip/hip_bf16.h>
#include <math.h>

#define NN 50000      // nodes
#define NE 500000     // edges (before self loops)
#define NP 10000      // pairs
#define FIN 128
#define HD 256
#define NE_TOT (NE + NN)   // with self loops

typedef __attribute__((ext_vector_type(8))) short bf16x8;
typedef __attribute__((ext_vector_type(4))) float f32x4;

// round-to-nearest-even fp32 -> bf16 bits
__device__ inline unsigned short f2bf(float f) {
  unsigned int u = __float_as_uint(f);
  unsigned int r = (u + 0x7fffu + ((u >> 16) & 1u)) >> 16;
  return (unsigned short)r;
}

// unpack 4 consecutive bf16 (as uint2) -> float4
__device__ inline float4 bf16x4_to_float4(uint2 u) {
  float4 r;
  r.x = __uint_as_float(u.x << 16);
  r.y = __uint_as_float(u.x & 0xffff0000u);
  r.z = __uint_as_float(u.y << 16);
  r.w = __uint_as_float(u.y & 0xffff0000u);
  return r;
}

// ---------------- weight transpose+convert: WT[n][k] = bf16(W[k][n]) ----------------
__global__ void transpose_convert(const float* __restrict__ W, unsigned short* __restrict__ WT,
                                  int K, int N) {
  int idx = blockIdx.x * 256 + threadIdx.x;
  if (idx >= K * N) return;
  int n = idx / K, k = idx - n * K;
  WT[idx] = f2bf(W[(size_t)k * N + n]);
}

// ---------------- bf16 MFMA GEMM + fused es/ed epilogue ----------------
// C[M,BN](bf16) = A[M,KTOT] @ B[KTOT,BN];  BT is B^T bf16 [BN][KTOT].
// es[r] += C_row . a_s (fp32 acc, atomicAdd partial per wave-half), ed likewise.
// Block: 64 rows, full BN cols. 4 waves in 2x2: wave tile 32 rows x BN/2 cols.
// K-loop BK=64; 16x16x32 MFMA; LDS rows padded to 72 bf16 (144B, 16B-aligned).
template <int BN, int KTOT, bool A_BF16>
__global__ __launch_bounds__(256)
void mfma_gemm(const void* __restrict__ Aptr, const unsigned short* __restrict__ BT,
               unsigned short* __restrict__ C, const float* __restrict__ a_s,
               const float* __restrict__ a_d, float* __restrict__ es, float* __restrict__ ed,
               int M) {
  constexpr int LDK = 72;
  constexpr int CN = BN / 2;   // cols per wave
  constexpr int NT = CN / 16;  // 16x16 col tiles per wave
  __shared__ unsigned short As[64][LDK];
  __shared__ unsigned short Bs[BN][LDK];
  const int tid = threadIdx.x;
  const int wave = tid >> 6;
  const int lane = tid & 63;
  const int quad = lane >> 4;
  const int l16 = lane & 15;
  const int wrow = wave >> 1;  // 0..1
  const int wcol = wave & 1;   // 0..1
  const int row0 = blockIdx.x * 64;

  f32x4 acc[2][NT] = {};

  for (int k0 = 0; k0 < KTOT; k0 += 64) {
    // stage A (64x64): 4 bf16 per thread per pass, 4 passes
#pragma unroll
    for (int p = 0; p < 4; p++) {
      int m = p * 16 + (tid >> 4);
      int k4 = (tid & 15) * 4;
      int gr = row0 + m;
      uint2 pk = make_uint2(0u, 0u);
      if (gr < M) {
        if (A_BF16) {
          pk = *(const uint2*)((const unsigned short*)Aptr + (size_t)gr * KTOT + k0 + k4);
        } else {
          float4 v = *(const float4*)((const float*)Aptr + (size_t)gr * KTOT + k0 + k4);
          pk.x = (unsigned int)f2bf(v.x) | ((unsigned int)f2bf(v.y) << 16);
          pk.y = (unsigned int)f2bf(v.z) | ((unsigned int)f2bf(v.w) << 16);
        }
      }
      *(uint2*)&As[m][k4] = pk;
    }
    // stage B^T (BNx64): 8 bf16 (16B) per thread, 32 rows per pass
#pragma unroll
    for (int p = 0; p < BN / 32; p++) {
      int n = p * 32 + (tid >> 3);
      int k8 = (tid & 7) * 8;
      *(uint4*)&Bs[n][k8] = *(const uint4*)(BT + (size_t)n * KTOT + k0 + k8);
    }
    __syncthreads();
#pragma unroll
    for (int ks = 0; ks < 2; ks++) {
      bf16x8 afrag[2];
#pragma unroll
      for (int rt = 0; rt < 2; rt++)
        afrag[rt] = *(const bf16x8*)&As[wrow * 32 + rt * 16 + l16][ks * 32 + quad * 8];
#pragma unroll
      for (int ct = 0; ct < NT; ct++) {
        bf16x8 bfrag = *(const bf16x8*)&Bs[wcol * CN + ct * 16 + l16][ks * 32 + quad * 8];
#pragma unroll
        for (int rt = 0; rt < 2; rt++)
          acc[rt][ct] = __builtin_amdgcn_mfma_f32_16x16x32_bf16(afrag[rt], bfrag, acc[rt][ct], 0, 0, 0);
      }
    }
    __syncthreads();
  }

  // epilogue: C(bf16) store + es/ed partial dots
  float asv[NT], adv[NT];
#pragma unroll
  for (int ct = 0; ct < NT; ct++) {
    asv[ct] = a_s[wcol * CN + ct * 16 + l16];
    adv[ct] = a_d[wcol * CN + ct * 16 + l16];
  }
#pragma unroll
  for (int rt = 0; rt < 2; rt++) {
#pragma unroll
    for (int r = 0; r < 4; r++) {
      int grow = row0 + wrow * 32 + rt * 16 + quad * 4 + r;
      bool ok = (grow < M);
      float ps = 0.f, pd = 0.f;
#pragma unroll
      for (int ct = 0; ct < NT; ct++) {
        float v = acc[rt][ct][r];
        ps += v * asv[ct];
        pd += v * adv[ct];
        if (ok) C[(size_t)grow * BN + wcol * CN + ct * 16 + l16] = f2bf(v);
      }
#pragma unroll
      for (int off = 1; off < 16; off <<= 1) {
        ps += __shfl_xor(ps, off, 16);
        pd += __shfl_xor(pd, off, 16);
      }
      if (l16 == 0 && ok) {
        atomicAdd(&es[grow], ps);
        atomicAdd(&ed[grow], pd);
      }
    }
  }
}

// ---------------- CSR build ----------------
__global__ void init_deg_kernel(int* __restrict__ deg, int n) {
  int i = blockIdx.x * blockDim.x + threadIdx.x;
  if (i < n) deg[i] = 1;  // self loop prebaked
}

__global__ void hist_kernel(const int* __restrict__ dst, int E, int* __restrict__ deg) {
  int e = blockIdx.x * blockDim.x + threadIdx.x;
  if (e < E) atomicAdd(&deg[dst[e]], 1);
}

__global__ void scan_phase1(const int* __restrict__ deg, int* __restrict__ incl,
                            int* __restrict__ bsum, int n) {
  __shared__ int tmp[256];
  int i = blockIdx.x * 256 + threadIdx.x;
  int v = (i < n) ? deg[i] : 0;
  tmp[threadIdx.x] = v;
  __syncthreads();
  for (int off = 1; off < 256; off <<= 1) {
    int t = (threadIdx.x >= off) ? tmp[threadIdx.x - off] : 0;
    __syncthreads();
    tmp[threadIdx.x] += t;
    __syncthreads();
  }
  if (i < n) incl[i] = tmp[threadIdx.x];
  if (threadIdx.x == 255) bsum[blockIdx.x] = tmp[255];
}

__global__ void scan_phase2(int* __restrict__ bsum, int nb) {
  __shared__ int tmp[256];
  int v = (threadIdx.x < nb) ? bsum[threadIdx.x] : 0;
  tmp[threadIdx.x] = v;
  __syncthreads();
  for (int off = 1; off < 256; off <<= 1) {
    int t = (threadIdx.x >= off) ? tmp[threadIdx.x - off] : 0;
    __syncthreads();
    tmp[threadIdx.x] += t;
    __syncthreads();
  }
  if (threadIdx.x < nb) bsum[threadIdx.x] = tmp[threadIdx.x] - v;  // exclusive
}

__global__ void scan_phase3(const int* __restrict__ deg, const int* __restrict__ incl,
                            const int* __restrict__ bsum, int* __restrict__ row_ptr,
                            int* __restrict__ cursor, int n, int total) {
  int i = blockIdx.x * 256 + threadIdx.x;
  if (i < n) {
    int excl = incl[i] - deg[i] + bsum[blockIdx.x];
    row_ptr[i] = excl;
    cursor[i] = excl;
  }
  if (i == n) row_ptr[n] = total;
}

__global__ void scatter_kernel(const int* __restrict__ src, const int* __restrict__ dst,
                               int E, int N, int* __restrict__ cursor, int* __restrict__ ssrc) {
  int e = blockIdx.x * blockDim.x + threadIdx.x;
  if (e < E) {
    int pos = atomicAdd(&cursor[dst[e]], 1);
    ssrc[pos] = src[e];
  } else if (e < E + N) {
    int i = e - E;
    int pos = atomicAdd(&cursor[i], 1);
    ssrc[pos] = i;
  }
}

// ---------------- edge softmax (one wave per dst node), unnormalized p + denom ----------------
__global__ void softmax_kernel(const int* __restrict__ row_ptr, const int* __restrict__ ssrc,
                               const float* __restrict__ es, const float* __restrict__ ed,
                               float* __restrict__ alpha, float* __restrict__ denom, int n) {
  int wid = (blockIdx.x * blockDim.x + threadIdx.x) >> 6;
  int lane = threadIdx.x & 63;
  if (wid >= n) return;
  int s = row_ptr[wid], e = row_ptr[wid + 1];
  float edv = ed[wid];
  float m = -1e30f;
  for (int p = s + lane; p < e; p += 64) {
    float l = es[ssrc[p]] + edv;
    l = (l > 0.f) ? l : 0.2f * l;
    m = fmaxf(m, l);
  }
#pragma unroll
  for (int off = 32; off; off >>= 1) m = fmaxf(m, __shfl_down(m, off));
  m = __shfl(m, 0);
  float sum = 0.f;
  for (int p = s + lane; p < e; p += 64) {
    float l = es[ssrc[p]] + edv;
    l = (l > 0.f) ? l : 0.2f * l;
    float pv = expf(l - m);
    alpha[p] = pv;
    sum += pv;
  }
#pragma unroll
  for (int off = 32; off; off >>= 1) sum += __shfl_down(sum, off);
  if (lane == 0) denom[wid] = sum;
}

// ---------------- aggregation: out[i][:] = (sum_e p[e]*h_bf16[src[e]][:]) / denom[i] + b ----------------
template <int F, bool RELU, bool OUT_BF16>
__global__ __launch_bounds__(256)
void aggregate_bf16(const int* __restrict__ row_ptr, const int* __restrict__ ssrc,
                    const float* __restrict__ alpha, const float* __restrict__ denom,
                    const unsigned short* __restrict__ h, const float* __restrict__ bias,
                    void* __restrict__ outp, int n) {
  constexpr int W = F / 4;  // 64 (F=256) or 32 (F=128)
  constexpr int NPB = 256 / W;
  int i = blockIdx.x * NPB + threadIdx.x / W;
  int ls = threadIdx.x & (W - 1);
  int s = row_ptr[i], e = row_ptr[i + 1];
  const unsigned short* hb = h + ls * 4;
  float4 acc0 = {0, 0, 0, 0}, acc1 = {0, 0, 0, 0}, acc2 = {0, 0, 0, 0}, acc3 = {0, 0, 0, 0};
  for (int p0 = s; p0 < e; p0 += W) {
    int p = p0 + ls;
    int msrc = 0;
    float ma = 0.f;
    if (p < e) { msrc = ssrc[p]; ma = alpha[p]; }
    int cnt = min(W, e - p0);
    int j = 0;
    for (; j + 4 <= cnt; j += 4) {
      int s0 = __shfl(msrc, j + 0, W), s1 = __shfl(msrc, j + 1, W);
      int s2 = __shfl(msrc, j + 2, W), s3 = __shfl(msrc, j + 3, W);
      float a0 = __shfl(ma, j + 0, W), a1 = __shfl(ma, j + 1, W);
      float a2 = __shfl(ma, j + 2, W), a3 = __shfl(ma, j + 3, W);
      float4 h0 = bf16x4_to_float4(*(const uint2*)(hb + (size_t)s0 * F));
      float4 h1 = bf16x4_to_float4(*(const uint2*)(hb + (size_t)s1 * F));
      float4 h2 = bf16x4_to_float4(*(const uint2*)(hb + (size_t)s2 * F));
      float4 h3 = bf16x4_to_float4(*(const uint2*)(hb + (size_t)s3 * F));
      acc0.x += a0 * h0.x; acc0.y += a0 * h0.y; acc0.z += a0 * h0.z; acc0.w += a0 * h0.w;
      acc1.x += a1 * h1.x; acc1.y += a1 * h1.y; acc1.z += a1 * h1.z; acc1.w += a1 * h1.w;
      acc2.x += a2 * h2.x; acc2.y += a2 * h2.y; acc2.z += a2 * h2.z; acc2.w += a2 * h2.w;
      acc3.x += a3 * h3.x; acc3.y += a3 * h3.y; acc3.z += a3 * h3.z; acc3.w += a3 * h3.w;
    }
    for (; j < cnt; j++) {
      int sj = __shfl(msrc, j, W);
      float aj = __shfl(ma, j, W);
      float4 hv = bf16x4_to_float4(*(const uint2*)(hb + (size_t)sj * F));
      acc0.x += aj * hv.x; acc0.y += aj * hv.y; acc0.z += aj * hv.z; acc0.w += aj * hv.w;
    }
  }
  float invd = 1.0f / denom[i];
  float4 b4 = *(const float4*)(bias + ls * 4);
  float4 r;
  r.x = (acc0.x + acc1.x + acc2.x + acc3.x) * invd + b4.x;
  r.y = (acc0.y + acc1.y + acc2.y + acc3.y) * invd + b4.y;
  r.z = (acc0.z + acc1.z + acc2.z + acc3.z) * invd + b4.z;
  r.w = (acc0.w + acc1.w + acc2.w + acc3.w) * invd + b4.w;
  if (RELU) {
    r.x = fmaxf(r.x, 0.f); r.y = fmaxf(r.y, 0.f);
    r.z = fmaxf(r.z, 0.f); r.w = fmaxf(r.w, 0.f);
  }
  if (OUT_BF16) {
    uint2 pk;
    pk.x = (unsigned int)f2bf(r.x) | ((unsigned int)f2bf(r.y) << 16);
    pk.y = (unsigned int)f2bf(r.z) | ((unsigned int)f2bf(r.w) << 16);
    *(uint2*)((unsigned short*)outp + (size_t)i * F + ls * 4) = pk;
  } else {
    *(float4*)((float*)outp + (size_t)i * F + ls * 4) = r;
  }
}

// ---------------- link predictor (one wave per pair, float2 per lane) ----------------
__global__ void predict_kernel(const float* __restrict__ h2, const int* __restrict__ mask,
                               const float* __restrict__ Wl, const float* __restrict__ bl,
                               float* __restrict__ out, int P) {
  int wid = (blockIdx.x * blockDim.x + threadIdx.x) >> 6;
  int lane = threadIdx.x & 63;
  if (wid >= P) return;
  int m0 = mask[wid * 2 + 0];
  int m1 = mask[wid * 2 + 1];
  float2 x0 = *(const float2*)(h2 + (size_t)m0 * FIN + lane * 2);
  float2 x1 = *(const float2*)(h2 + (size_t)m1 * FIN + lane * 2);
  float2 w0 = *(const float2*)(Wl + lane * 2);
  float2 w1 = *(const float2*)(Wl + FIN + lane * 2);
  float s = x0.x * w0.x + x0.y * w0.y + x1.x * w1.x + x1.y * w1.y;
#pragma unroll
  for (int off = 32; off; off >>= 1) s += __shfl_down(s, off);
  if (lane == 0) {
    float z = s + bl[0];
    out[wid] = 1.0f / (1.0f + expf(-z));
  }
}

extern "C" void kernel_launch(void* const* d_in, const int* in_sizes, int n_in,
                              void* d_out, int out_size, void* d_ws, size_t ws_size,
                              hipStream_t stream) {
  const float* features = (const float*)d_in[0];
  const int* edge_index = (const int*)d_in[1];
  const int* mask       = (const int*)d_in[2];
  const float* W1     = (const float*)d_in[3];
  const float* a_src1 = (const float*)d_in[4];
  const float* a_dst1 = (const float*)d_in[5];
  const float* b1     = (const float*)d_in[6];
  const float* W2     = (const float*)d_in[7];
  const float* a_src2 = (const float*)d_in[8];
  const float* a_dst2 = (const float*)d_in[9];
  const float* b2     = (const float*)d_in[10];
  const float* Wl     = (const float*)d_in[11];
  const float* bl     = (const float*)d_in[12];
  float* out = (float*)d_out;

  const int* src = edge_index;        // [E]
  const int* dst = edge_index + NE;   // [E]

  // ---- workspace layout ----
  char* ws = (char*)d_ws;
  size_t off = 0;
  auto alloc = [&](size_t bytes) {
    void* p = ws + off;
    off += (bytes + 255) & ~(size_t)255;
    return p;
  };
  unsigned short* h_buf = (unsigned short*)alloc((size_t)NN * HD * 2);   // h1/h2 bf16
  unsigned short* x2b   = (unsigned short*)alloc((size_t)NN * HD * 2);   // relu(out1) bf16
  float* out2    = (float*)alloc((size_t)NN * FIN * 4);                  // layer2 agg out fp32
  unsigned short* W1T = (unsigned short*)alloc((size_t)HD * FIN * 2);    // [256][128]
  unsigned short* W2T = (unsigned short*)alloc((size_t)FIN * HD * 2);    // [128][256]
  float* es_buf  = (float*)alloc((size_t)NN * 4);
  float* ed_buf  = (float*)alloc((size_t)NN * 4);
  float* denom   = (float*)alloc((size_t)NN * 4);
  float* alpha   = (float*)alloc((size_t)NE_TOT * 4);
  int* deg       = (int*)alloc((size_t)NN * 4);
  int* incl      = (int*)alloc((size_t)NN * 4);
  int* bsum      = (int*)alloc(1024);
  int* row_ptr   = (int*)alloc((size_t)(NN + 1) * 4);
  int* cursor    = (int*)alloc((size_t)NN * 4);
  int* ssrc      = (int*)alloc((size_t)NE_TOT * 4);
  (void)ws_size; (void)in_sizes; (void)n_in; (void)out_size;

  const int nblk_n256 = (NN + 255) / 256;          // 196
  const int nblk_wavepn = (NN * 64 + 255) / 256;   // 12500
  const int nblk_gemm = (NN + 63) / 64;            // 782

  // ---- CSR build ----
  init_deg_kernel<<<nblk_n256, 256, 0, stream>>>(deg, NN);
  hist_kernel<<<(NE + 255) / 256, 256, 0, stream>>>(dst, NE, deg);
  scan_phase1<<<nblk_n256, 256, 0, stream>>>(deg, incl, bsum, NN);
  scan_phase2<<<1, 256, 0, stream>>>(bsum, nblk_n256);
  scan_phase3<<<nblk_n256 + 1, 256, 0, stream>>>(deg, incl, bsum, row_ptr, cursor, NN, NE_TOT);
  scatter_kernel<<<(NE_TOT + 255) / 256, 256, 0, stream>>>(src, dst, NE, NN, cursor, ssrc);

  // ---- weight transpose+convert ----
  transpose_convert<<<(FIN * HD + 255) / 256, 256, 0, stream>>>(W1, W1T, FIN, HD);  // [K=128,N=256]
  transpose_convert<<<(FIN * HD + 255) / 256, 256, 0, stream>>>(W2, W2T, HD, FIN);  // [K=256,N=128]

  // ---- layer 1: h1 = X @ W1 (MFMA bf16) + fused es/ed ----
  hipMemsetAsync(es_buf, 0, (size_t)NN * 4, stream);
  hipMemsetAsync(ed_buf, 0, (size_t)NN * 4, stream);
  mfma_gemm<HD, FIN, false><<<nblk_gemm, 256, 0, stream>>>(
      (const void*)features, W1T, h_buf, a_src1, a_dst1, es_buf, ed_buf, NN);
  softmax_kernel<<<nblk_wavepn, 256, 0, stream>>>(row_ptr, ssrc, es_buf, ed_buf, alpha, denom, NN);
  aggregate_bf16<HD, true, true><<<NN / 4, 256, 0, stream>>>(row_ptr, ssrc, alpha, denom, h_buf, b1, x2b, NN);

  // ---- layer 2: h2 = x2 @ W2 (MFMA bf16) + fused es/ed ----
  hipMemsetAsync(es_buf, 0, (size_t)NN * 4, stream);
  hipMemsetAsync(ed_buf, 0, (size_t)NN * 4, stream);
  mfma_gemm<FIN, HD, true><<<nblk_gemm, 256, 0, stream>>>(
      (const void*)x2b, W2T, h_buf, a_src2, a_dst2, es_buf, ed_buf, NN);
  softmax_kernel<<<nblk_wavepn, 256, 0, stream>>>(row_ptr, ssrc, es_buf, ed_buf, alpha, denom, NN);
  aggregate_bf16<FIN, false, false><<<NN / 8, 256, 0, stream>>>(row_ptr, ssrc, alpha, denom, h_buf, b2, out2, NN);

  // ---- link predictor ----
  predict_kernel<<<(NP * 64 + 255) / 256, 256, 0, stream>>>(out2, mask, Wl, bl, out, NP);
}

// Round 5
// 275.412 us; speedup vs baseline: 1.9128x; 1.0657x over previous
//
#include <hip/hip_runtime.h>
#include <hip/hip_bf16.h>
#include <math.h>

#define NN 50000      // nodes
#define NE 500000     // edges (before self loops)
#define NP 10000      // pairs
#define FIN 128
#define HD 256
#define NE_TOT (NE + NN)   // with self loops

typedef __attribute__((ext_vector_type(8))) short bf16x8;
typedef __attribute__((ext_vector_type(4))) float f32x4;

// round-to-nearest-even fp32 -> bf16 bits
__device__ inline unsigned short f2bf(float f) {
  unsigned int u = __float_as_uint(f);
  unsigned int r = (u + 0x7fffu + ((u >> 16) & 1u)) >> 16;
  return (unsigned short)r;
}

// unpack 4 consecutive bf16 (as uint2) -> float4
__device__ inline float4 bf16x4_to_float4(uint2 u) {
  float4 r;
  r.x = __uint_as_float(u.x << 16);
  r.y = __uint_as_float(u.x & 0xffff0000u);
  r.z = __uint_as_float(u.y << 16);
  r.w = __uint_as_float(u.y & 0xffff0000u);
  return r;
}

// ---------------- weight transpose+convert: WT[n][k] = bf16(W[k][n]) ----------------
__global__ void transpose_convert(const float* __restrict__ W, unsigned short* __restrict__ WT,
                                  int K, int N) {
  int idx = blockIdx.x * 256 + threadIdx.x;
  if (idx >= K * N) return;
  int n = idx / K, k = idx - n * K;
  WT[idx] = f2bf(W[(size_t)k * N + n]);
}

// ---------------- bf16 MFMA GEMM + fused es/ed epilogue ----------------
// C[M,BN](bf16) = A[M,KTOT] @ B[KTOT,BN];  BT is B^T bf16 [BN][KTOT].
// Block: 64 rows, full BN cols. 4 waves in 2x2: wave tile 32 rows x BN/2 cols.
template <int BN, int KTOT, bool A_BF16>
__global__ __launch_bounds__(256)
void mfma_gemm(const void* __restrict__ Aptr, const unsigned short* __restrict__ BT,
               unsigned short* __restrict__ C, const float* __restrict__ a_s,
               const float* __restrict__ a_d, float* __restrict__ es, float* __restrict__ ed,
               int M) {
  constexpr int LDK = 72;
  constexpr int CN = BN / 2;   // cols per wave
  constexpr int NT = CN / 16;  // 16x16 col tiles per wave
  __shared__ unsigned short As[64][LDK];
  __shared__ unsigned short Bs[BN][LDK];
  const int tid = threadIdx.x;
  const int wave = tid >> 6;
  const int lane = tid & 63;
  const int quad = lane >> 4;
  const int l16 = lane & 15;
  const int wrow = wave >> 1;  // 0..1
  const int wcol = wave & 1;   // 0..1
  const int row0 = blockIdx.x * 64;

  f32x4 acc[2][NT] = {};

  for (int k0 = 0; k0 < KTOT; k0 += 64) {
#pragma unroll
    for (int p = 0; p < 4; p++) {
      int m = p * 16 + (tid >> 4);
      int k4 = (tid & 15) * 4;
      int gr = row0 + m;
      uint2 pk = make_uint2(0u, 0u);
      if (gr < M) {
        if (A_BF16) {
          pk = *(const uint2*)((const unsigned short*)Aptr + (size_t)gr * KTOT + k0 + k4);
        } else {
          float4 v = *(const float4*)((const float*)Aptr + (size_t)gr * KTOT + k0 + k4);
          pk.x = (unsigned int)f2bf(v.x) | ((unsigned int)f2bf(v.y) << 16);
          pk.y = (unsigned int)f2bf(v.z) | ((unsigned int)f2bf(v.w) << 16);
        }
      }
      *(uint2*)&As[m][k4] = pk;
    }
#pragma unroll
    for (int p = 0; p < BN / 32; p++) {
      int n = p * 32 + (tid >> 3);
      int k8 = (tid & 7) * 8;
      *(uint4*)&Bs[n][k8] = *(const uint4*)(BT + (size_t)n * KTOT + k0 + k8);
    }
    __syncthreads();
#pragma unroll
    for (int ks = 0; ks < 2; ks++) {
      bf16x8 afrag[2];
#pragma unroll
      for (int rt = 0; rt < 2; rt++)
        afrag[rt] = *(const bf16x8*)&As[wrow * 32 + rt * 16 + l16][ks * 32 + quad * 8];
#pragma unroll
      for (int ct = 0; ct < NT; ct++) {
        bf16x8 bfrag = *(const bf16x8*)&Bs[wcol * CN + ct * 16 + l16][ks * 32 + quad * 8];
#pragma unroll
        for (int rt = 0; rt < 2; rt++)
          acc[rt][ct] = __builtin_amdgcn_mfma_f32_16x16x32_bf16(afrag[rt], bfrag, acc[rt][ct], 0, 0, 0);
      }
    }
    __syncthreads();
  }

  float asv[NT], adv[NT];
#pragma unroll
  for (int ct = 0; ct < NT; ct++) {
    asv[ct] = a_s[wcol * CN + ct * 16 + l16];
    adv[ct] = a_d[wcol * CN + ct * 16 + l16];
  }
#pragma unroll
  for (int rt = 0; rt < 2; rt++) {
#pragma unroll
    for (int r = 0; r < 4; r++) {
      int grow = row0 + wrow * 32 + rt * 16 + quad * 4 + r;
      bool ok = (grow < M);
      float ps = 0.f, pd = 0.f;
#pragma unroll
      for (int ct = 0; ct < NT; ct++) {
        float v = acc[rt][ct][r];
        ps += v * asv[ct];
        pd += v * adv[ct];
        if (ok) C[(size_t)grow * BN + wcol * CN + ct * 16 + l16] = f2bf(v);
      }
#pragma unroll
      for (int off = 1; off < 16; off <<= 1) {
        ps += __shfl_xor(ps, off, 16);
        pd += __shfl_xor(pd, off, 16);
      }
      if (l16 == 0 && ok) {
        atomicAdd(&es[grow], ps);
        atomicAdd(&ed[grow], pd);
      }
    }
  }
}

// ---------------- CSR build ----------------
__global__ void init_deg_kernel(int* __restrict__ deg, int n) {
  int i = blockIdx.x * blockDim.x + threadIdx.x;
  if (i < n) deg[i] = 1;  // self loop prebaked
}

__global__ void hist_kernel(const int* __restrict__ dst, int E, int* __restrict__ deg) {
  int e = blockIdx.x * blockDim.x + threadIdx.x;
  if (e < E) atomicAdd(&deg[dst[e]], 1);
}

__global__ void scan_phase1(const int* __restrict__ deg, int* __restrict__ incl,
                            int* __restrict__ bsum, int n) {
  __shared__ int tmp[256];
  int i = blockIdx.x * 256 + threadIdx.x;
  int v = (i < n) ? deg[i] : 0;
  tmp[threadIdx.x] = v;
  __syncthreads();
  for (int off = 1; off < 256; off <<= 1) {
    int t = (threadIdx.x >= off) ? tmp[threadIdx.x - off] : 0;
    __syncthreads();
    tmp[threadIdx.x] += t;
    __syncthreads();
  }
  if (i < n) incl[i] = tmp[threadIdx.x];
  if (threadIdx.x == 255) bsum[blockIdx.x] = tmp[255];
}

__global__ void scan_phase2(int* __restrict__ bsum, int nb) {
  __shared__ int tmp[256];
  int v = (threadIdx.x < nb) ? bsum[threadIdx.x] : 0;
  tmp[threadIdx.x] = v;
  __syncthreads();
  for (int off = 1; off < 256; off <<= 1) {
    int t = (threadIdx.x >= off) ? tmp[threadIdx.x - off] : 0;
    __syncthreads();
    tmp[threadIdx.x] += t;
    __syncthreads();
  }
  if (threadIdx.x < nb) bsum[threadIdx.x] = tmp[threadIdx.x] - v;  // exclusive
}

__global__ void scan_phase3(const int* __restrict__ deg, const int* __restrict__ incl,
                            const int* __restrict__ bsum, int* __restrict__ row_ptr,
                            int* __restrict__ cursor, int n, int total) {
  int i = blockIdx.x * 256 + threadIdx.x;
  if (i < n) {
    int excl = incl[i] - deg[i] + bsum[blockIdx.x];
    row_ptr[i] = excl;
    cursor[i] = excl;
  }
  if (i == n) row_ptr[n] = total;
}

__global__ void scatter_kernel(const int* __restrict__ src, const int* __restrict__ dst,
                               int E, int N, int* __restrict__ cursor, int* __restrict__ ssrc) {
  int e = blockIdx.x * blockDim.x + threadIdx.x;
  if (e < E) {
    int pos = atomicAdd(&cursor[dst[e]], 1);
    ssrc[pos] = src[e];
  } else if (e < E + N) {
    int i = e - E;
    int pos = atomicAdd(&cursor[i], 1);
    ssrc[pos] = i;
  }
}

// ---------------- mask node set: flag + compact ----------------
__global__ void flag_kernel(const int* __restrict__ mask, int n2, int* __restrict__ flags) {
  int t = blockIdx.x * 256 + threadIdx.x;
  if (t < n2) flags[mask[t]] = 1;
}

__global__ void compact_kernel(const int* __restrict__ flags, int* __restrict__ list,
                               int* __restrict__ cnt, int n) {
  int i = blockIdx.x * 256 + threadIdx.x;
  if (i < n && flags[i]) {
    int p = atomicAdd(cnt, 1);
    list[p] = i;
  }
}

// ---------------- fused online-softmax + aggregation ----------------
// out[i][:] = (sum_e exp(l_e - M)*h[src_e][:]) / (sum_e exp(l_e - M)) + bias
// l_e = leaky_relu(es[src_e] + ed[i], 0.2); M = max_e l_e (online).
// W = F/4 lanes per node; per W-chunk: parallel es gather + reduce, then
// shfl-broadcast (src, p) for float4 row accumulation.
template <int F, bool RELU, bool OUT_BF16, bool USE_LIST>
__global__ __launch_bounds__(256)
void fused_agg(const int* __restrict__ row_ptr, const int* __restrict__ ssrc,
               const float* __restrict__ es, const float* __restrict__ ed,
               const unsigned short* __restrict__ h, const float* __restrict__ bias,
               void* __restrict__ outp, const int* __restrict__ node_list,
               const int* __restrict__ node_cnt) {
  constexpr int W = F / 4;  // 64 (F=256) or 32 (F=128)
  constexpr int NPB = 256 / W;
  int idx = blockIdx.x * NPB + threadIdx.x / W;
  int ls = threadIdx.x & (W - 1);
  int i;
  if (USE_LIST) {
    if (idx >= *node_cnt) return;
    i = node_list[idx];
  } else {
    i = idx;
  }
  int s = row_ptr[i], e = row_ptr[i + 1];
  float edv = ed[i];
  const unsigned short* hb = h + ls * 4;
  float4 acc0 = {0, 0, 0, 0}, acc1 = {0, 0, 0, 0}, acc2 = {0, 0, 0, 0}, acc3 = {0, 0, 0, 0};
  float M = -1e30f, l = 0.f;
  for (int p0 = s; p0 < e; p0 += W) {
    int p = p0 + ls;
    int msrc = 0;
    float logit = -1e30f;
    if (p < e) {
      msrc = ssrc[p];
      float t = es[msrc] + edv;
      logit = (t > 0.f) ? t : 0.2f * t;
    }
    // chunk max over the W-lane group
    float cm = logit;
#pragma unroll
    for (int off = W / 2; off; off >>= 1) cm = fmaxf(cm, __shfl_xor(cm, off, W));
    float Mn = fmaxf(M, cm);
    float rf = expf(M - Mn);   // 0 on first chunk, usually 1 after
    float pv = expf(logit - Mn);  // 0 for inactive lanes
    float cs = pv;
#pragma unroll
    for (int off = W / 2; off; off >>= 1) cs += __shfl_xor(cs, off, W);
    l = l * rf + cs;
    M = Mn;
    acc0.x *= rf; acc0.y *= rf; acc0.z *= rf; acc0.w *= rf;
    acc1.x *= rf; acc1.y *= rf; acc1.z *= rf; acc1.w *= rf;
    acc2.x *= rf; acc2.y *= rf; acc2.z *= rf; acc2.w *= rf;
    acc3.x *= rf; acc3.y *= rf; acc3.z *= rf; acc3.w *= rf;
    int cnt = min(W, e - p0);
    int j = 0;
    for (; j + 4 <= cnt; j += 4) {
      int s0 = __shfl(msrc, j + 0, W), s1 = __shfl(msrc, j + 1, W);
      int s2 = __shfl(msrc, j + 2, W), s3 = __shfl(msrc, j + 3, W);
      float a0 = __shfl(pv, j + 0, W), a1 = __shfl(pv, j + 1, W);
      float a2 = __shfl(pv, j + 2, W), a3 = __shfl(pv, j + 3, W);
      float4 h0 = bf16x4_to_float4(*(const uint2*)(hb + (size_t)s0 * F));
      float4 h1 = bf16x4_to_float4(*(const uint2*)(hb + (size_t)s1 * F));
      float4 h2 = bf16x4_to_float4(*(const uint2*)(hb + (size_t)s2 * F));
      float4 h3 = bf16x4_to_float4(*(const uint2*)(hb + (size_t)s3 * F));
      acc0.x += a0 * h0.x; acc0.y += a0 * h0.y; acc0.z += a0 * h0.z; acc0.w += a0 * h0.w;
      acc1.x += a1 * h1.x; acc1.y += a1 * h1.y; acc1.z += a1 * h1.z; acc1.w += a1 * h1.w;
      acc2.x += a2 * h2.x; acc2.y += a2 * h2.y; acc2.z += a2 * h2.z; acc2.w += a2 * h2.w;
      acc3.x += a3 * h3.x; acc3.y += a3 * h3.y; acc3.z += a3 * h3.z; acc3.w += a3 * h3.w;
    }
    for (; j < cnt; j++) {
      int sj = __shfl(msrc, j, W);
      float aj = __shfl(pv, j, W);
      float4 hv = bf16x4_to_float4(*(const uint2*)(hb + (size_t)sj * F));
      acc0.x += aj * hv.x; acc0.y += aj * hv.y; acc0.z += aj * hv.z; acc0.w += aj * hv.w;
    }
  }
  float invd = 1.0f / l;
  float4 b4 = *(const float4*)(bias + ls * 4);
  float4 r;
  r.x = (acc0.x + acc1.x + acc2.x + acc3.x) * invd + b4.x;
  r.y = (acc0.y + acc1.y + acc2.y + acc3.y) * invd + b4.y;
  r.z = (acc0.z + acc1.z + acc2.z + acc3.z) * invd + b4.z;
  r.w = (acc0.w + acc1.w + acc2.w + acc3.w) * invd + b4.w;
  if (RELU) {
    r.x = fmaxf(r.x, 0.f); r.y = fmaxf(r.y, 0.f);
    r.z = fmaxf(r.z, 0.f); r.w = fmaxf(r.w, 0.f);
  }
  if (OUT_BF16) {
    uint2 pk;
    pk.x = (unsigned int)f2bf(r.x) | ((unsigned int)f2bf(r.y) << 16);
    pk.y = (unsigned int)f2bf(r.z) | ((unsigned int)f2bf(r.w) << 16);
    *(uint2*)((unsigned short*)outp + (size_t)i * F + ls * 4) = pk;
  } else {
    *(float4*)((float*)outp + (size_t)i * F + ls * 4) = r;
  }
}

// ---------------- link predictor (one wave per pair, float2 per lane) ----------------
__global__ void predict_kernel(const float* __restrict__ h2, const int* __restrict__ mask,
                               const float* __restrict__ Wl, const float* __restrict__ bl,
                               float* __restrict__ out, int P) {
  int wid = (blockIdx.x * blockDim.x + threadIdx.x) >> 6;
  int lane = threadIdx.x & 63;
  if (wid >= P) return;
  int m0 = mask[wid * 2 + 0];
  int m1 = mask[wid * 2 + 1];
  float2 x0 = *(const float2*)(h2 + (size_t)m0 * FIN + lane * 2);
  float2 x1 = *(const float2*)(h2 + (size_t)m1 * FIN + lane * 2);
  float2 w0 = *(const float2*)(Wl + lane * 2);
  float2 w1 = *(const float2*)(Wl + FIN + lane * 2);
  float s = x0.x * w0.x + x0.y * w0.y + x1.x * w1.x + x1.y * w1.y;
#pragma unroll
  for (int off = 32; off; off >>= 1) s += __shfl_down(s, off);
  if (lane == 0) {
    float z = s + bl[0];
    out[wid] = 1.0f / (1.0f + expf(-z));
  }
}

extern "C" void kernel_launch(void* const* d_in, const int* in_sizes, int n_in,
                              void* d_out, int out_size, void* d_ws, size_t ws_size,
                              hipStream_t stream) {
  const float* features = (const float*)d_in[0];
  const int* edge_index = (const int*)d_in[1];
  const int* mask       = (const int*)d_in[2];
  const float* W1     = (const float*)d_in[3];
  const float* a_src1 = (const float*)d_in[4];
  const float* a_dst1 = (const float*)d_in[5];
  const float* b1     = (const float*)d_in[6];
  const float* W2     = (const float*)d_in[7];
  const float* a_src2 = (const float*)d_in[8];
  const float* a_dst2 = (const float*)d_in[9];
  const float* b2     = (const float*)d_in[10];
  const float* Wl     = (const float*)d_in[11];
  const float* bl     = (const float*)d_in[12];
  float* out = (float*)d_out;

  const int* src = edge_index;        // [E]
  const int* dst = edge_index + NE;   // [E]

  // ---- workspace layout ----
  char* ws = (char*)d_ws;
  size_t off = 0;
  auto alloc = [&](size_t bytes) {
    void* p = ws + off;
    off += (bytes + 255) & ~(size_t)255;
    return p;
  };
  unsigned short* h_buf = (unsigned short*)alloc((size_t)NN * HD * 2);   // h1/h2 bf16
  unsigned short* x2b   = (unsigned short*)alloc((size_t)NN * HD * 2);   // relu(out1) bf16
  float* out2    = (float*)alloc((size_t)NN * FIN * 4);                  // layer2 agg out fp32
  unsigned short* W1T = (unsigned short*)alloc((size_t)HD * FIN * 2);    // [256][128]
  unsigned short* W2T = (unsigned short*)alloc((size_t)FIN * HD * 2);    // [128][256]
  float* es_buf  = (float*)alloc((size_t)NN * 4);
  float* ed_buf  = (float*)alloc((size_t)NN * 4);
  int* deg       = (int*)alloc((size_t)NN * 4);
  int* incl      = (int*)alloc((size_t)NN * 4);
  int* bsum      = (int*)alloc(1024);
  int* row_ptr   = (int*)alloc((size_t)(NN + 1) * 4);
  int* cursor    = (int*)alloc((size_t)NN * 4);
  int* ssrc      = (int*)alloc((size_t)NE_TOT * 4);
  int* flags     = (int*)alloc((size_t)NN * 4);
  int* node_list = (int*)alloc((size_t)NN * 4);
  int* node_cnt  = (int*)alloc(256);
  (void)ws_size; (void)in_sizes; (void)n_in; (void)out_size;

  const int nblk_n256 = (NN + 255) / 256;          // 196
  const int nblk_gemm = (NN + 63) / 64;            // 782

  // ---- CSR build ----
  init_deg_kernel<<<nblk_n256, 256, 0, stream>>>(deg, NN);
  hist_kernel<<<(NE + 255) / 256, 256, 0, stream>>>(dst, NE, deg);
  scan_phase1<<<nblk_n256, 256, 0, stream>>>(deg, incl, bsum, NN);
  scan_phase2<<<1, 256, 0, stream>>>(bsum, nblk_n256);
  scan_phase3<<<nblk_n256 + 1, 256, 0, stream>>>(deg, incl, bsum, row_ptr, cursor, NN, NE_TOT);
  scatter_kernel<<<(NE_TOT + 255) / 256, 256, 0, stream>>>(src, dst, NE, NN, cursor, ssrc);

  // ---- masked-node set (for layer-2 restriction) ----
  hipMemsetAsync(flags, 0, (size_t)NN * 4, stream);
  hipMemsetAsync(node_cnt, 0, 4, stream);
  flag_kernel<<<(2 * NP + 255) / 256, 256, 0, stream>>>(mask, 2 * NP, flags);
  compact_kernel<<<nblk_n256, 256, 0, stream>>>(flags, node_list, node_cnt, NN);

  // ---- weight transpose+convert ----
  transpose_convert<<<(FIN * HD + 255) / 256, 256, 0, stream>>>(W1, W1T, FIN, HD);  // [K=128,N=256]
  transpose_convert<<<(FIN * HD + 255) / 256, 256, 0, stream>>>(W2, W2T, HD, FIN);  // [K=256,N=128]

  // ---- layer 1: h1 = X @ W1 (MFMA bf16) + fused es/ed ----
  hipMemsetAsync(es_buf, 0, (size_t)NN * 4, stream);
  hipMemsetAsync(ed_buf, 0, (size_t)NN * 4, stream);
  mfma_gemm<HD, FIN, false><<<nblk_gemm, 256, 0, stream>>>(
      (const void*)features, W1T, h_buf, a_src1, a_dst1, es_buf, ed_buf, NN);
  // fused online-softmax + aggregation (all nodes), bf16 out
  fused_agg<HD, true, true, false><<<NN / 4, 256, 0, stream>>>(
      row_ptr, ssrc, es_buf, ed_buf, h_buf, b1, x2b, nullptr, nullptr);

  // ---- layer 2: h2 = x2 @ W2 (MFMA bf16) + fused es/ed ----
  hipMemsetAsync(es_buf, 0, (size_t)NN * 4, stream);
  hipMemsetAsync(ed_buf, 0, (size_t)NN * 4, stream);
  mfma_gemm<FIN, HD, true><<<nblk_gemm, 256, 0, stream>>>(
      (const void*)x2b, W2T, h_buf, a_src2, a_dst2, es_buf, ed_buf, NN);
  // fused agg restricted to masked dst nodes, fp32 out
  fused_agg<FIN, false, false, true><<<(NN + 7) / 8, 256, 0, stream>>>(
      row_ptr, ssrc, es_buf, ed_buf, h_buf, b2, out2, node_list, node_cnt);

  // ---- link predictor ----
  predict_kernel<<<(NP * 64 + 255) / 256, 256, 0, stream>>>(out2, mask, Wl, bl, out, NP);
}

// Round 6
// 274.308 us; speedup vs baseline: 1.9205x; 1.0040x over previous
//
#include <hip/hip_runtime.h>
#include <hip/hip_bf16.h>
#include <math.h>

#define NN 50000      // nodes
#define NE 500000     // edges (before self loops)
#define NP 10000      // pairs
#define FIN 128
#define HD 256
#define NE_TOT (NE + NN)   // with self loops

typedef __attribute__((ext_vector_type(8))) short bf16x8;
typedef __attribute__((ext_vector_type(4))) float f32x4;

// round-to-nearest-even fp32 -> bf16 bits
__device__ inline unsigned short f2bf(float f) {
  unsigned int u = __float_as_uint(f);
  unsigned int r = (u + 0x7fffu + ((u >> 16) & 1u)) >> 16;
  return (unsigned short)r;
}

// load VEC consecutive bf16 and unpack to float
template <int VEC>
__device__ inline void row_load(const unsigned short* p, float* f) {
  if constexpr (VEC == 8) {
    uint4 u = *(const uint4*)p;
    f[0] = __uint_as_float(u.x << 16); f[1] = __uint_as_float(u.x & 0xffff0000u);
    f[2] = __uint_as_float(u.y << 16); f[3] = __uint_as_float(u.y & 0xffff0000u);
    f[4] = __uint_as_float(u.z << 16); f[5] = __uint_as_float(u.z & 0xffff0000u);
    f[6] = __uint_as_float(u.w << 16); f[7] = __uint_as_float(u.w & 0xffff0000u);
  } else {
    uint2 u = *(const uint2*)p;
    f[0] = __uint_as_float(u.x << 16); f[1] = __uint_as_float(u.x & 0xffff0000u);
    f[2] = __uint_as_float(u.y << 16); f[3] = __uint_as_float(u.y & 0xffff0000u);
  }
}

// ---------------- weight transpose+convert: WT[n][k] = bf16(W[k][n]) ----------------
__global__ void transpose_convert(const float* __restrict__ W, unsigned short* __restrict__ WT,
                                  int K, int N) {
  int idx = blockIdx.x * 256 + threadIdx.x;
  if (idx >= K * N) return;
  int n = idx / K, k = idx - n * K;
  WT[idx] = f2bf(W[(size_t)k * N + n]);
}

// ---------------- bf16 MFMA GEMM + fused es/ed epilogue ----------------
// C[M,BN](bf16) = A[M,KTOT] @ B[KTOT,BN];  BT is B^T bf16 [BN][KTOT].
// Block: 64 rows, full BN cols. 4 waves in 2x2: wave tile 32 rows x BN/2 cols.
template <int BN, int KTOT, bool A_BF16>
__global__ __launch_bounds__(256)
void mfma_gemm(const void* __restrict__ Aptr, const unsigned short* __restrict__ BT,
               unsigned short* __restrict__ C, const float* __restrict__ a_s,
               const float* __restrict__ a_d, float* __restrict__ es, float* __restrict__ ed,
               int M) {
  constexpr int LDK = 72;
  constexpr int CN = BN / 2;   // cols per wave
  constexpr int NT = CN / 16;  // 16x16 col tiles per wave
  __shared__ unsigned short As[64][LDK];
  __shared__ unsigned short Bs[BN][LDK];
  const int tid = threadIdx.x;
  const int wave = tid >> 6;
  const int lane = tid & 63;
  const int quad = lane >> 4;
  const int l16 = lane & 15;
  const int wrow = wave >> 1;  // 0..1
  const int wcol = wave & 1;   // 0..1
  const int row0 = blockIdx.x * 64;

  f32x4 acc[2][NT] = {};

  for (int k0 = 0; k0 < KTOT; k0 += 64) {
#pragma unroll
    for (int p = 0; p < 4; p++) {
      int m = p * 16 + (tid >> 4);
      int k4 = (tid & 15) * 4;
      int gr = row0 + m;
      uint2 pk = make_uint2(0u, 0u);
      if (gr < M) {
        if (A_BF16) {
          pk = *(const uint2*)((const unsigned short*)Aptr + (size_t)gr * KTOT + k0 + k4);
        } else {
          float4 v = *(const float4*)((const float*)Aptr + (size_t)gr * KTOT + k0 + k4);
          pk.x = (unsigned int)f2bf(v.x) | ((unsigned int)f2bf(v.y) << 16);
          pk.y = (unsigned int)f2bf(v.z) | ((unsigned int)f2bf(v.w) << 16);
        }
      }
      *(uint2*)&As[m][k4] = pk;
    }
#pragma unroll
    for (int p = 0; p < BN / 32; p++) {
      int n = p * 32 + (tid >> 3);
      int k8 = (tid & 7) * 8;
      *(uint4*)&Bs[n][k8] = *(const uint4*)(BT + (size_t)n * KTOT + k0 + k8);
    }
    __syncthreads();
#pragma unroll
    for (int ks = 0; ks < 2; ks++) {
      bf16x8 afrag[2];
#pragma unroll
      for (int rt = 0; rt < 2; rt++)
        afrag[rt] = *(const bf16x8*)&As[wrow * 32 + rt * 16 + l16][ks * 32 + quad * 8];
#pragma unroll
      for (int ct = 0; ct < NT; ct++) {
        bf16x8 bfrag = *(const bf16x8*)&Bs[wcol * CN + ct * 16 + l16][ks * 32 + quad * 8];
#pragma unroll
        for (int rt = 0; rt < 2; rt++)
          acc[rt][ct] = __builtin_amdgcn_mfma_f32_16x16x32_bf16(afrag[rt], bfrag, acc[rt][ct], 0, 0, 0);
      }
    }
    __syncthreads();
  }

  float asv[NT], adv[NT];
#pragma unroll
  for (int ct = 0; ct < NT; ct++) {
    asv[ct] = a_s[wcol * CN + ct * 16 + l16];
    adv[ct] = a_d[wcol * CN + ct * 16 + l16];
  }
#pragma unroll
  for (int rt = 0; rt < 2; rt++) {
#pragma unroll
    for (int r = 0; r < 4; r++) {
      int grow = row0 + wrow * 32 + rt * 16 + quad * 4 + r;
      bool ok = (grow < M);
      float ps = 0.f, pd = 0.f;
#pragma unroll
      for (int ct = 0; ct < NT; ct++) {
        float v = acc[rt][ct][r];
        ps += v * asv[ct];
        pd += v * adv[ct];
        if (ok) C[(size_t)grow * BN + wcol * CN + ct * 16 + l16] = f2bf(v);
      }
#pragma unroll
      for (int off = 1; off < 16; off <<= 1) {
        ps += __shfl_xor(ps, off, 16);
        pd += __shfl_xor(pd, off, 16);
      }
      if (l16 == 0 && ok) {
        atomicAdd(&es[grow], ps);
        atomicAdd(&ed[grow], pd);
      }
    }
  }
}

// ---------------- CSR build ----------------
__global__ void init_deg_kernel(int* __restrict__ deg, int n) {
  int i = blockIdx.x * blockDim.x + threadIdx.x;
  if (i < n) deg[i] = 1;  // self loop prebaked
}

__global__ void hist_kernel(const int* __restrict__ dst, int E, int* __restrict__ deg) {
  int e = blockIdx.x * blockDim.x + threadIdx.x;
  if (e < E) atomicAdd(&deg[dst[e]], 1);
}

__global__ void scan_phase1(const int* __restrict__ deg, int* __restrict__ incl,
                            int* __restrict__ bsum, int n) {
  __shared__ int tmp[256];
  int i = blockIdx.x * 256 + threadIdx.x;
  int v = (i < n) ? deg[i] : 0;
  tmp[threadIdx.x] = v;
  __syncthreads();
  for (int off = 1; off < 256; off <<= 1) {
    int t = (threadIdx.x >= off) ? tmp[threadIdx.x - off] : 0;
    __syncthreads();
    tmp[threadIdx.x] += t;
    __syncthreads();
  }
  if (i < n) incl[i] = tmp[threadIdx.x];
  if (threadIdx.x == 255) bsum[blockIdx.x] = tmp[255];
}

__global__ void scan_phase2(int* __restrict__ bsum, int nb) {
  __shared__ int tmp[256];
  int v = (threadIdx.x < nb) ? bsum[threadIdx.x] : 0;
  tmp[threadIdx.x] = v;
  __syncthreads();
  for (int off = 1; off < 256; off <<= 1) {
    int t = (threadIdx.x >= off) ? tmp[threadIdx.x - off] : 0;
    __syncthreads();
    tmp[threadIdx.x] += t;
    __syncthreads();
  }
  if (threadIdx.x < nb) bsum[threadIdx.x] = tmp[threadIdx.x] - v;  // exclusive
}

__global__ void scan_phase3(const int* __restrict__ deg, const int* __restrict__ incl,
                            const int* __restrict__ bsum, int* __restrict__ row_ptr,
                            int* __restrict__ cursor, int n, int total) {
  int i = blockIdx.x * 256 + threadIdx.x;
  if (i < n) {
    int excl = incl[i] - deg[i] + bsum[blockIdx.x];
    row_ptr[i] = excl;
    cursor[i] = excl;
  }
  if (i == n) row_ptr[n] = total;
}

__global__ void scatter_kernel(const int* __restrict__ src, const int* __restrict__ dst,
                               int E, int N, int* __restrict__ cursor, int* __restrict__ ssrc) {
  int e = blockIdx.x * blockDim.x + threadIdx.x;
  if (e < E) {
    int pos = atomicAdd(&cursor[dst[e]], 1);
    ssrc[pos] = src[e];
  } else if (e < E + N) {
    int i = e - E;
    int pos = atomicAdd(&cursor[i], 1);
    ssrc[pos] = i;
  }
}

// ---------------- mask node set: flag + compact ----------------
__global__ void flag_kernel(const int* __restrict__ mask, int n2, int* __restrict__ flags) {
  int t = blockIdx.x * 256 + threadIdx.x;
  if (t < n2) flags[mask[t]] = 1;
}

__global__ void compact_kernel(const int* __restrict__ flags, int* __restrict__ list,
                               int* __restrict__ cnt, int n) {
  int i = blockIdx.x * 256 + threadIdx.x;
  if (i < n && flags[i]) {
    int p = atomicAdd(cnt, 1);
    list[p] = i;
  }
}

// ---------------- fused two-phase softmax + aggregation ----------------
// out[i][:] = (sum_e exp(l_e - M)*h[src_e][:]) / (sum_e exp(l_e - M)) + bias
// l_e = leaky_relu(es[src_e] + ed[i], 0.2); M = max_e l_e.
// 32 lanes per node (2 nodes per wave), VEC = F/32 bf16 per lane (16B loads for F=256).
// Phase 1: max (first chunk cached in regs — avg degree 11 => usually single chunk).
// Phase 2: exp + sum + shfl-broadcast row accumulation, 4-edge unroll.
template <int F, bool RELU, bool OUT_BF16, bool USE_LIST>
__global__ __launch_bounds__(256)
void fused_agg(const int* __restrict__ row_ptr, const int* __restrict__ ssrc,
               const float* __restrict__ es, const float* __restrict__ ed,
               const unsigned short* __restrict__ h, const float* __restrict__ bias,
               void* __restrict__ outp, const int* __restrict__ node_list,
               const int* __restrict__ node_cnt) {
  constexpr int VEC = F / 32;  // 8 (F=256) or 4 (F=128)
  int idx = blockIdx.x * 8 + (threadIdx.x >> 5);
  int ls = threadIdx.x & 31;
  int i;
  if (USE_LIST) {
    if (idx >= *node_cnt) return;
    i = node_list[idx];
  } else {
    i = idx;
  }
  int s = row_ptr[i], e = row_ptr[i + 1];
  float edv = ed[i];

  // phase 1: row max; cache first chunk in registers
  int msrc0 = 0;
  float logit0 = -1e30f;
  {
    int p = s + ls;
    if (p < e) {
      msrc0 = ssrc[p];
      float t = es[msrc0] + edv;
      logit0 = (t > 0.f) ? t : 0.2f * t;
    }
  }
  float M = logit0;
  for (int p0 = s + 32; p0 < e; p0 += 32) {  // rare: deg > 32
    int p = p0 + ls;
    if (p < e) {
      int ms = ssrc[p];
      float t = es[ms] + edv;
      float lg = (t > 0.f) ? t : 0.2f * t;
      M = fmaxf(M, lg);
    }
  }
#pragma unroll
  for (int off = 16; off; off >>= 1) M = fmaxf(M, __shfl_xor(M, off, 32));

  // phase 2: exp, sum, gather-accumulate
  float accA[VEC] = {}, accB[VEC] = {};
  float lsum = 0.f;
  const unsigned short* hb = h + ls * VEC;
  for (int p0 = s; p0 < e; p0 += 32) {
    int msrc;
    float logit;
    if (p0 == s) {
      msrc = msrc0;
      logit = logit0;
    } else {
      int p = p0 + ls;
      msrc = 0;
      logit = -1e30f;
      if (p < e) {
        msrc = ssrc[p];
        float t = es[msrc] + edv;
        logit = (t > 0.f) ? t : 0.2f * t;
      }
    }
    float pv = __expf(logit - M);  // 0 for inactive lanes
    lsum += pv;
    int cnt = min(32, e - p0);
    int j = 0;
    for (; j + 4 <= cnt; j += 4) {
      int s0 = __shfl(msrc, j + 0, 32), s1 = __shfl(msrc, j + 1, 32);
      int s2 = __shfl(msrc, j + 2, 32), s3 = __shfl(msrc, j + 3, 32);
      float a0 = __shfl(pv, j + 0, 32), a1 = __shfl(pv, j + 1, 32);
      float a2 = __shfl(pv, j + 2, 32), a3 = __shfl(pv, j + 3, 32);
      float f0[VEC], f1[VEC], f2[VEC], f3[VEC];
      row_load<VEC>(hb + (size_t)s0 * F, f0);
      row_load<VEC>(hb + (size_t)s1 * F, f1);
      row_load<VEC>(hb + (size_t)s2 * F, f2);
      row_load<VEC>(hb + (size_t)s3 * F, f3);
#pragma unroll
      for (int v = 0; v < VEC; v++) {
        accA[v] += a0 * f0[v];
        accB[v] += a1 * f1[v];
        accA[v] += a2 * f2[v];
        accB[v] += a3 * f3[v];
      }
    }
    for (; j < cnt; j++) {
      int sj = __shfl(msrc, j, 32);
      float aj = __shfl(pv, j, 32);
      float fj[VEC];
      row_load<VEC>(hb + (size_t)sj * F, fj);
#pragma unroll
      for (int v = 0; v < VEC; v++) accA[v] += aj * fj[v];
    }
  }
#pragma unroll
  for (int off = 16; off; off >>= 1) lsum += __shfl_xor(lsum, off, 32);
  float invd = 1.0f / lsum;

  float r[VEC];
#pragma unroll
  for (int v = 0; v < VEC; v++) {
    r[v] = (accA[v] + accB[v]) * invd + bias[ls * VEC + v];
    if (RELU) r[v] = fmaxf(r[v], 0.f);
  }
  if (OUT_BF16) {
    unsigned short* op = (unsigned short*)outp + (size_t)i * F + ls * VEC;
    if constexpr (VEC == 8) {
      uint4 pk;
      pk.x = (unsigned int)f2bf(r[0]) | ((unsigned int)f2bf(r[1]) << 16);
      pk.y = (unsigned int)f2bf(r[2]) | ((unsigned int)f2bf(r[3]) << 16);
      pk.z = (unsigned int)f2bf(r[4]) | ((unsigned int)f2bf(r[5]) << 16);
      pk.w = (unsigned int)f2bf(r[6]) | ((unsigned int)f2bf(r[7]) << 16);
      *(uint4*)op = pk;
    } else {
      uint2 pk;
      pk.x = (unsigned int)f2bf(r[0]) | ((unsigned int)f2bf(r[1]) << 16);
      pk.y = (unsigned int)f2bf(r[2]) | ((unsigned int)f2bf(r[3]) << 16);
      *(uint2*)op = pk;
    }
  } else {
    float* op = (float*)outp + (size_t)i * F + ls * VEC;
#pragma unroll
    for (int v = 0; v < VEC; v += 4)
      *(float4*)(op + v) = make_float4(r[v], r[v + 1], r[v + 2], r[v + 3]);
  }
}

// ---------------- link predictor (one wave per pair, float2 per lane) ----------------
__global__ void predict_kernel(const float* __restrict__ h2, const int* __restrict__ mask,
                               const float* __restrict__ Wl, const float* __restrict__ bl,
                               float* __restrict__ out, int P) {
  int wid = (blockIdx.x * blockDim.x + threadIdx.x) >> 6;
  int lane = threadIdx.x & 63;
  if (wid >= P) return;
  int m0 = mask[wid * 2 + 0];
  int m1 = mask[wid * 2 + 1];
  float2 x0 = *(const float2*)(h2 + (size_t)m0 * FIN + lane * 2);
  float2 x1 = *(const float2*)(h2 + (size_t)m1 * FIN + lane * 2);
  float2 w0 = *(const float2*)(Wl + lane * 2);
  float2 w1 = *(const float2*)(Wl + FIN + lane * 2);
  float s = x0.x * w0.x + x0.y * w0.y + x1.x * w1.x + x1.y * w1.y;
#pragma unroll
  for (int off = 32; off; off >>= 1) s += __shfl_down(s, off);
  if (lane == 0) {
    float z = s + bl[0];
    out[wid] = 1.0f / (1.0f + expf(-z));
  }
}

extern "C" void kernel_launch(void* const* d_in, const int* in_sizes, int n_in,
                              void* d_out, int out_size, void* d_ws, size_t ws_size,
                              hipStream_t stream) {
  const float* features = (const float*)d_in[0];
  const int* edge_index = (const int*)d_in[1];
  const int* mask       = (const int*)d_in[2];
  const float* W1     = (const float*)d_in[3];
  const float* a_src1 = (const float*)d_in[4];
  const float* a_dst1 = (const float*)d_in[5];
  const float* b1     = (const float*)d_in[6];
  const float* W2     = (const float*)d_in[7];
  const float* a_src2 = (const float*)d_in[8];
  const float* a_dst2 = (const float*)d_in[9];
  const float* b2     = (const float*)d_in[10];
  const float* Wl     = (const float*)d_in[11];
  const float* bl     = (const float*)d_in[12];
  float* out = (float*)d_out;

  const int* src = edge_index;        // [E]
  const int* dst = edge_index + NE;   // [E]

  // ---- workspace layout ----
  char* ws = (char*)d_ws;
  size_t off = 0;
  auto alloc = [&](size_t bytes) {
    void* p = ws + off;
    off += (bytes + 255) & ~(size_t)255;
    return p;
  };
  unsigned short* h_buf = (unsigned short*)alloc((size_t)NN * HD * 2);   // h1/h2 bf16
  unsigned short* x2b   = (unsigned short*)alloc((size_t)NN * HD * 2);   // relu(out1) bf16
  float* out2    = (float*)alloc((size_t)NN * FIN * 4);                  // layer2 agg out fp32
  unsigned short* W1T = (unsigned short*)alloc((size_t)HD * FIN * 2);    // [256][128]
  unsigned short* W2T = (unsigned short*)alloc((size_t)FIN * HD * 2);    // [128][256]
  float* es_buf  = (float*)alloc((size_t)NN * 4);
  float* ed_buf  = (float*)alloc((size_t)NN * 4);
  int* deg       = (int*)alloc((size_t)NN * 4);
  int* incl      = (int*)alloc((size_t)NN * 4);
  int* bsum      = (int*)alloc(1024);
  int* row_ptr   = (int*)alloc((size_t)(NN + 1) * 4);
  int* cursor    = (int*)alloc((size_t)NN * 4);
  int* ssrc      = (int*)alloc((size_t)NE_TOT * 4);
  int* flags     = (int*)alloc((size_t)NN * 4);
  int* node_list = (int*)alloc((size_t)NN * 4);
  int* node_cnt  = (int*)alloc(256);
  (void)ws_size; (void)in_sizes; (void)n_in; (void)out_size;

  const int nblk_n256 = (NN + 255) / 256;          // 196
  const int nblk_gemm = (NN + 63) / 64;            // 782

  // ---- CSR build ----
  init_deg_kernel<<<nblk_n256, 256, 0, stream>>>(deg, NN);
  hist_kernel<<<(NE + 255) / 256, 256, 0, stream>>>(dst, NE, deg);
  scan_phase1<<<nblk_n256, 256, 0, stream>>>(deg, incl, bsum, NN);
  scan_phase2<<<1, 256, 0, stream>>>(bsum, nblk_n256);
  scan_phase3<<<nblk_n256 + 1, 256, 0, stream>>>(deg, incl, bsum, row_ptr, cursor, NN, NE_TOT);
  scatter_kernel<<<(NE_TOT + 255) / 256, 256, 0, stream>>>(src, dst, NE, NN, cursor, ssrc);

  // ---- masked-node set (for layer-2 restriction) ----
  hipMemsetAsync(flags, 0, (size_t)NN * 4, stream);
  hipMemsetAsync(node_cnt, 0, 4, stream);
  flag_kernel<<<(2 * NP + 255) / 256, 256, 0, stream>>>(mask, 2 * NP, flags);
  compact_kernel<<<nblk_n256, 256, 0, stream>>>(flags, node_list, node_cnt, NN);

  // ---- weight transpose+convert ----
  transpose_convert<<<(FIN * HD + 255) / 256, 256, 0, stream>>>(W1, W1T, FIN, HD);  // [K=128,N=256]
  transpose_convert<<<(FIN * HD + 255) / 256, 256, 0, stream>>>(W2, W2T, HD, FIN);  // [K=256,N=128]

  // ---- layer 1: h1 = X @ W1 (MFMA bf16) + fused es/ed ----
  hipMemsetAsync(es_buf, 0, (size_t)NN * 4, stream);
  hipMemsetAsync(ed_buf, 0, (size_t)NN * 4, stream);
  mfma_gemm<HD, FIN, false><<<nblk_gemm, 256, 0, stream>>>(
      (const void*)features, W1T, h_buf, a_src1, a_dst1, es_buf, ed_buf, NN);
  // fused softmax + aggregation (all nodes), bf16 out
  fused_agg<HD, true, true, false><<<NN / 8, 256, 0, stream>>>(
      row_ptr, ssrc, es_buf, ed_buf, h_buf, b1, x2b, nullptr, nullptr);

  // ---- layer 2: h2 = x2 @ W2 (MFMA bf16) + fused es/ed ----
  hipMemsetAsync(es_buf, 0, (size_t)NN * 4, stream);
  hipMemsetAsync(ed_buf, 0, (size_t)NN * 4, stream);
  mfma_gemm<FIN, HD, true><<<nblk_gemm, 256, 0, stream>>>(
      (const void*)x2b, W2T, h_buf, a_src2, a_dst2, es_buf, ed_buf, NN);
  // fused agg restricted to masked dst nodes (cnt <= 2*NP), fp32 out
  fused_agg<FIN, false, false, true><<<(2 * NP + 7) / 8, 256, 0, stream>>>(
      row_ptr, ssrc, es_buf, ed_buf, h_buf, b2, out2, node_list, node_cnt);

  // ---- link predictor ----
  predict_kernel<<<(NP * 64 + 255) / 256, 256, 0, stream>>>(out2, mask, Wl, bl, out, NP);
}

// Round 7
// 257.041 us; speedup vs baseline: 2.0495x; 1.0672x over previous
//
#include <hip/hip_runtime.h>
#include <hip/hip_bf16.h>
#include <math.h>

#define NN 50000      // nodes
#define NE 500000     // edges (before self loops)
#define NP 10000      // pairs
#define FIN 128
#define HD 256
#define NE_TOT (NE + NN)   // with self loops

typedef __attribute__((ext_vector_type(8))) short bf16x8;
typedef __attribute__((ext_vector_type(4))) float f32x4;

// round-to-nearest-even fp32 -> bf16 bits
__device__ inline unsigned short f2bf(float f) {
  unsigned int u = __float_as_uint(f);
  unsigned int r = (u + 0x7fffu + ((u >> 16) & 1u)) >> 16;
  return (unsigned short)r;
}

__device__ inline float bflo(unsigned int u) { return __uint_as_float(u << 16); }
__device__ inline float bfhi(unsigned int u) { return __uint_as_float(u & 0xffff0000u); }

// ---------------- merged init: deg=1 (self loop), flags=0, node_cnt=0 ----------------
__global__ void init_misc(int* __restrict__ deg, int* __restrict__ flags,
                          int* __restrict__ node_cnt, int n) {
  int i = blockIdx.x * 256 + threadIdx.x;
  if (i < n) { deg[i] = 1; flags[i] = 0; }
  if (i == 0) *node_cnt = 0;
}

// ---------------- merged weight transpose+convert (both layers) ----------------
__global__ void prep_weights(const float* __restrict__ W1, const float* __restrict__ W2,
                             unsigned short* __restrict__ W1T, unsigned short* __restrict__ W2T) {
  int idx = blockIdx.x * 256 + threadIdx.x;
  if (idx < FIN * HD) {
    // W1 [FIN][HD] -> W1T[n][k], n<HD, k<FIN
    int n = idx / FIN, k = idx - n * FIN;
    W1T[idx] = f2bf(W1[(size_t)k * HD + n]);
  } else if (idx < 2 * FIN * HD) {
    int id2 = idx - FIN * HD;
    // W2 [HD][FIN] -> W2T[n][k], n<FIN, k<HD
    int n = id2 / HD, k = id2 - n * HD;
    W2T[id2] = f2bf(W2[(size_t)k * FIN + n]);
  }
}

// ---------------- bf16 MFMA GEMM + fused es/ed epilogue (LDS reduce, plain store) ----------------
// C[M,BN](bf16) = A[M,KTOT] @ B[KTOT,BN];  BT is B^T bf16 [BN][KTOT].
// Block: 64 rows, full BN cols. 4 waves in 2x2: wave tile 32 rows x BN/2 cols.
template <int BN, int KTOT, bool A_BF16>
__global__ __launch_bounds__(256)
void mfma_gemm(const void* __restrict__ Aptr, const unsigned short* __restrict__ BT,
               unsigned short* __restrict__ C, const float* __restrict__ a_s,
               const float* __restrict__ a_d, float* __restrict__ es, float* __restrict__ ed,
               int M) {
  constexpr int LDK = 72;
  constexpr int CN = BN / 2;   // cols per wave
  constexpr int NT = CN / 16;  // 16x16 col tiles per wave
  __shared__ unsigned short As[64][LDK];
  __shared__ unsigned short Bs[BN][LDK];
  __shared__ float esl[64][2];
  __shared__ float edl[64][2];
  const int tid = threadIdx.x;
  const int wave = tid >> 6;
  const int lane = tid & 63;
  const int quad = lane >> 4;
  const int l16 = lane & 15;
  const int wrow = wave >> 1;  // 0..1
  const int wcol = wave & 1;   // 0..1
  const int row0 = blockIdx.x * 64;

  f32x4 acc[2][NT] = {};

  for (int k0 = 0; k0 < KTOT; k0 += 64) {
#pragma unroll
    for (int p = 0; p < 4; p++) {
      int m = p * 16 + (tid >> 4);
      int k4 = (tid & 15) * 4;
      int gr = row0 + m;
      uint2 pk = make_uint2(0u, 0u);
      if (gr < M) {
        if (A_BF16) {
          pk = *(const uint2*)((const unsigned short*)Aptr + (size_t)gr * KTOT + k0 + k4);
        } else {
          float4 v = *(const float4*)((const float*)Aptr + (size_t)gr * KTOT + k0 + k4);
          pk.x = (unsigned int)f2bf(v.x) | ((unsigned int)f2bf(v.y) << 16);
          pk.y = (unsigned int)f2bf(v.z) | ((unsigned int)f2bf(v.w) << 16);
        }
      }
      *(uint2*)&As[m][k4] = pk;
    }
#pragma unroll
    for (int p = 0; p < BN / 32; p++) {
      int n = p * 32 + (tid >> 3);
      int k8 = (tid & 7) * 8;
      *(uint4*)&Bs[n][k8] = *(const uint4*)(BT + (size_t)n * KTOT + k0 + k8);
    }
    __syncthreads();
#pragma unroll
    for (int ks = 0; ks < 2; ks++) {
      bf16x8 afrag[2];
#pragma unroll
      for (int rt = 0; rt < 2; rt++)
        afrag[rt] = *(const bf16x8*)&As[wrow * 32 + rt * 16 + l16][ks * 32 + quad * 8];
#pragma unroll
      for (int ct = 0; ct < NT; ct++) {
        bf16x8 bfrag = *(const bf16x8*)&Bs[wcol * CN + ct * 16 + l16][ks * 32 + quad * 8];
#pragma unroll
        for (int rt = 0; rt < 2; rt++)
          acc[rt][ct] = __builtin_amdgcn_mfma_f32_16x16x32_bf16(afrag[rt], bfrag, acc[rt][ct], 0, 0, 0);
      }
    }
    __syncthreads();
  }

  float asv[NT], adv[NT];
#pragma unroll
  for (int ct = 0; ct < NT; ct++) {
    asv[ct] = a_s[wcol * CN + ct * 16 + l16];
    adv[ct] = a_d[wcol * CN + ct * 16 + l16];
  }
#pragma unroll
  for (int rt = 0; rt < 2; rt++) {
#pragma unroll
    for (int r = 0; r < 4; r++) {
      int lrow = wrow * 32 + rt * 16 + quad * 4 + r;
      int grow = row0 + lrow;
      bool ok = (grow < M);
      float ps = 0.f, pd = 0.f;
#pragma unroll
      for (int ct = 0; ct < NT; ct++) {
        float v = acc[rt][ct][r];
        ps += v * asv[ct];
        pd += v * adv[ct];
        if (ok) C[(size_t)grow * BN + wcol * CN + ct * 16 + l16] = f2bf(v);
      }
#pragma unroll
      for (int off = 1; off < 16; off <<= 1) {
        ps += __shfl_xor(ps, off, 16);
        pd += __shfl_xor(pd, off, 16);
      }
      if (l16 == 0) {
        esl[lrow][wcol] = ps;
        edl[lrow][wcol] = pd;
      }
    }
  }
  __syncthreads();
  if (tid < 64) {
    int grow = row0 + tid;
    if (grow < M) {
      es[grow] = esl[tid][0] + esl[tid][1];
      ed[grow] = edl[tid][0] + edl[tid][1];
    }
  }
}

// ---------------- CSR build ----------------
__global__ void hist_kernel(const int* __restrict__ dst, int E, int* __restrict__ deg) {
  int e = blockIdx.x * blockDim.x + threadIdx.x;
  if (e < E) atomicAdd(&deg[dst[e]], 1);
}

__global__ void scan_phase1(const int* __restrict__ deg, int* __restrict__ incl,
                            int* __restrict__ bsum, int n) {
  __shared__ int tmp[256];
  int i = blockIdx.x * 256 + threadIdx.x;
  int v = (i < n) ? deg[i] : 0;
  tmp[threadIdx.x] = v;
  __syncthreads();
  for (int off = 1; off < 256; off <<= 1) {
    int t = (threadIdx.x >= off) ? tmp[threadIdx.x - off] : 0;
    __syncthreads();
    tmp[threadIdx.x] += t;
    __syncthreads();
  }
  if (i < n) incl[i] = tmp[threadIdx.x];
  if (threadIdx.x == 255) bsum[blockIdx.x] = tmp[255];
}

__global__ void scan_phase2(int* __restrict__ bsum, int nb) {
  __shared__ int tmp[256];
  int v = (threadIdx.x < nb) ? bsum[threadIdx.x] : 0;
  tmp[threadIdx.x] = v;
  __syncthreads();
  for (int off = 1; off < 256; off <<= 1) {
    int t = (threadIdx.x >= off) ? tmp[threadIdx.x - off] : 0;
    __syncthreads();
    tmp[threadIdx.x] += t;
    __syncthreads();
  }
  if (threadIdx.x < nb) bsum[threadIdx.x] = tmp[threadIdx.x] - v;  // exclusive
}

__global__ void scan_phase3(const int* __restrict__ deg, const int* __restrict__ incl,
                            const int* __restrict__ bsum, int* __restrict__ row_ptr,
                            int* __restrict__ cursor, int n, int total) {
  int i = blockIdx.x * 256 + threadIdx.x;
  if (i < n) {
    int excl = incl[i] - deg[i] + bsum[blockIdx.x];
    row_ptr[i] = excl;
    cursor[i] = excl;
  }
  if (i == n) row_ptr[n] = total;
}

__global__ void scatter_kernel(const int* __restrict__ src, const int* __restrict__ dst,
                               int E, int N, int* __restrict__ cursor, int* __restrict__ ssrc) {
  int e = blockIdx.x * blockDim.x + threadIdx.x;
  if (e < E) {
    int pos = atomicAdd(&cursor[dst[e]], 1);
    ssrc[pos] = src[e];
  } else if (e < E + N) {
    int i = e - E;
    int pos = atomicAdd(&cursor[i], 1);
    ssrc[pos] = i;
  }
}

// ---------------- mask node set: flag + compact ----------------
__global__ void flag_kernel(const int* __restrict__ mask, int n2, int* __restrict__ flags) {
  int t = blockIdx.x * 256 + threadIdx.x;
  if (t < n2) flags[mask[t]] = 1;
}

__global__ void compact_kernel(const int* __restrict__ flags, int* __restrict__ list,
                               int* __restrict__ cnt, int n) {
  int i = blockIdx.x * 256 + threadIdx.x;
  if (i < n && flags[i]) {
    int p = atomicAdd(cnt, 1);
    list[p] = i;
  }
}

// ---------------- fused softmax+agg, one node per 64-lane wave (F=256) ----------------
// Per edge: (src, weight) broadcast via readlane -> SGPR; row load dwordx2 with
// uniform base (saddr path); uniform trip counts (no divergence).
__global__ __launch_bounds__(256)
void fused_agg64(const int* __restrict__ row_ptr, const int* __restrict__ ssrc,
                 const float* __restrict__ es, const float* __restrict__ ed,
                 const unsigned short* __restrict__ h, const float* __restrict__ bias,
                 unsigned short* __restrict__ outp, int n) {
  int i = blockIdx.x * 4 + (threadIdx.x >> 6);
  int lane = threadIdx.x & 63;
  if (i >= n) return;
  int s = row_ptr[i], e = row_ptr[i + 1];
  int deg = e - s;
  float edv = ed[i];

  // phase 1: chunk-0 logits cached; extra chunks (deg>64: ~never) for max
  int msrc0 = 0;
  float logit0 = -1e30f;
  if (lane < deg) {
    msrc0 = ssrc[s + lane];
    float t = es[msrc0] + edv;
    logit0 = (t > 0.f) ? t : 0.2f * t;
  }
  float mloc = logit0;
  for (int p0 = s + 64; p0 < e; p0 += 64) {
    int p = p0 + lane;
    if (p < e) {
      int ms = ssrc[p];
      float t = es[ms] + edv;
      float lg = (t > 0.f) ? t : 0.2f * t;
      mloc = fmaxf(mloc, lg);
    }
  }
#pragma unroll
  for (int off = 32; off; off >>= 1) mloc = fmaxf(mloc, __shfl_xor(mloc, off, 64));

  // phase 2: exp + accumulate (uniform readlane broadcast, 8-edge load batches)
  float pv = (lane < deg) ? __expf(logit0 - mloc) : 0.f;
  float lsum = pv;
  unsigned int pvu = __float_as_uint(pv);
  float acc0 = 0.f, acc1 = 0.f, acc2 = 0.f, acc3 = 0.f;
  const unsigned short* hb = h + lane * 4;  // 8 B per lane, 512 B per row-load
  int cnt0 = min(deg, 64);
  int j = 0;
  for (; j + 8 <= cnt0; j += 8) {
    uint2 r[8];
    float w[8];
#pragma unroll
    for (int u = 0; u < 8; u++) {
      int sj = __builtin_amdgcn_readlane(msrc0, j + u);
      w[u] = __uint_as_float(__builtin_amdgcn_readlane(pvu, j + u));
      r[u] = *(const uint2*)(hb + (size_t)sj * HD);
    }
#pragma unroll
    for (int u = 0; u < 8; u++) {
      acc0 += w[u] * bflo(r[u].x);
      acc1 += w[u] * bfhi(r[u].x);
      acc2 += w[u] * bflo(r[u].y);
      acc3 += w[u] * bfhi(r[u].y);
    }
  }
  for (; j < cnt0; j++) {
    int sj = __builtin_amdgcn_readlane(msrc0, j);
    float wj = __uint_as_float(__builtin_amdgcn_readlane(pvu, j));
    uint2 rv = *(const uint2*)(hb + (size_t)sj * HD);
    acc0 += wj * bflo(rv.x);
    acc1 += wj * bfhi(rv.x);
    acc2 += wj * bflo(rv.y);
    acc3 += wj * bfhi(rv.y);
  }
  // rare: deg > 64
  for (int p0 = s + 64; p0 < e; p0 += 64) {
    int p = p0 + lane;
    int ms = 0;
    float lg = -1e30f;
    if (p < e) {
      ms = ssrc[p];
      float t = es[ms] + edv;
      lg = (t > 0.f) ? t : 0.2f * t;
    }
    float pvc = (p < e) ? __expf(lg - mloc) : 0.f;
    lsum += pvc;
    unsigned int pvcu = __float_as_uint(pvc);
    int cnt = min(64, e - p0);
    for (int jj = 0; jj < cnt; jj++) {
      int sj = __builtin_amdgcn_readlane(ms, jj);
      float wj = __uint_as_float(__builtin_amdgcn_readlane(pvcu, jj));
      uint2 rv = *(const uint2*)(hb + (size_t)sj * HD);
      acc0 += wj * bflo(rv.x);
      acc1 += wj * bfhi(rv.x);
      acc2 += wj * bflo(rv.y);
      acc3 += wj * bfhi(rv.y);
    }
  }
#pragma unroll
  for (int off = 32; off; off >>= 1) lsum += __shfl_xor(lsum, off, 64);
  float invd = 1.0f / lsum;
  float4 b4 = *(const float4*)(bias + lane * 4);
  float r0 = fmaxf(acc0 * invd + b4.x, 0.f);   // relu (layer 1 only)
  float r1 = fmaxf(acc1 * invd + b4.y, 0.f);
  float r2 = fmaxf(acc2 * invd + b4.z, 0.f);
  float r3 = fmaxf(acc3 * invd + b4.w, 0.f);
  uint2 pk;
  pk.x = (unsigned int)f2bf(r0) | ((unsigned int)f2bf(r1) << 16);
  pk.y = (unsigned int)f2bf(r2) | ((unsigned int)f2bf(r3) << 16);
  *(uint2*)(outp + (size_t)i * HD + lane * 4) = pk;
}

// ---------------- layer-2 fused agg (32 lanes/node, masked list, fp32 out) ----------------
__global__ __launch_bounds__(256)
void fused_agg_l2(const int* __restrict__ row_ptr, const int* __restrict__ ssrc,
                  const float* __restrict__ es, const float* __restrict__ ed,
                  const unsigned short* __restrict__ h, const float* __restrict__ bias,
                  float* __restrict__ outp, const int* __restrict__ node_list,
                  const int* __restrict__ node_cnt) {
  constexpr int F = FIN;
  constexpr int VEC = 4;
  int idx = blockIdx.x * 8 + (threadIdx.x >> 5);
  int ls = threadIdx.x & 31;
  if (idx >= *node_cnt) return;
  int i = node_list[idx];
  int s = row_ptr[i], e = row_ptr[i + 1];
  float edv = ed[i];

  int msrc0 = 0;
  float logit0 = -1e30f;
  {
    int p = s + ls;
    if (p < e) {
      msrc0 = ssrc[p];
      float t = es[msrc0] + edv;
      logit0 = (t > 0.f) ? t : 0.2f * t;
    }
  }
  float M = logit0;
  for (int p0 = s + 32; p0 < e; p0 += 32) {
    int p = p0 + ls;
    if (p < e) {
      int ms = ssrc[p];
      float t = es[ms] + edv;
      float lg = (t > 0.f) ? t : 0.2f * t;
      M = fmaxf(M, lg);
    }
  }
#pragma unroll
  for (int off = 16; off; off >>= 1) M = fmaxf(M, __shfl_xor(M, off, 32));

  float accA[VEC] = {}, accB[VEC] = {};
  float lsum = 0.f;
  const unsigned short* hb = h + ls * VEC;
  for (int p0 = s; p0 < e; p0 += 32) {
    int msrc;
    float logit;
    if (p0 == s) {
      msrc = msrc0;
      logit = logit0;
    } else {
      int p = p0 + ls;
      msrc = 0;
      logit = -1e30f;
      if (p < e) {
        msrc = ssrc[p];
        float t = es[msrc] + edv;
        logit = (t > 0.f) ? t : 0.2f * t;
      }
    }
    float pv = __expf(logit - M);
    lsum += pv;
    int cnt = min(32, e - p0);
    int j = 0;
    for (; j + 4 <= cnt; j += 4) {
      int s0 = __shfl(msrc, j + 0, 32), s1 = __shfl(msrc, j + 1, 32);
      int s2 = __shfl(msrc, j + 2, 32), s3 = __shfl(msrc, j + 3, 32);
      float a0 = __shfl(pv, j + 0, 32), a1 = __shfl(pv, j + 1, 32);
      float a2 = __shfl(pv, j + 2, 32), a3 = __shfl(pv, j + 3, 32);
      uint2 u0 = *(const uint2*)(hb + (size_t)s0 * F);
      uint2 u1 = *(const uint2*)(hb + (size_t)s1 * F);
      uint2 u2 = *(const uint2*)(hb + (size_t)s2 * F);
      uint2 u3 = *(const uint2*)(hb + (size_t)s3 * F);
      accA[0] += a0 * bflo(u0.x); accA[1] += a0 * bfhi(u0.x);
      accA[2] += a0 * bflo(u0.y); accA[3] += a0 * bfhi(u0.y);
      accB[0] += a1 * bflo(u1.x); accB[1] += a1 * bfhi(u1.x);
      accB[2] += a1 * bflo(u1.y); accB[3] += a1 * bfhi(u1.y);
      accA[0] += a2 * bflo(u2.x); accA[1] += a2 * bfhi(u2.x);
      accA[2] += a2 * bflo(u2.y); accA[3] += a2 * bfhi(u2.y);
      accB[0] += a3 * bflo(u3.x); accB[1] += a3 * bfhi(u3.x);
      accB[2] += a3 * bflo(u3.y); accB[3] += a3 * bfhi(u3.y);
    }
    for (; j < cnt; j++) {
      int sj = __shfl(msrc, j, 32);
      float aj = __shfl(pv, j, 32);
      uint2 uv = *(const uint2*)(hb + (size_t)sj * F);
      accA[0] += aj * bflo(uv.x); accA[1] += aj * bfhi(uv.x);
      accA[2] += aj * bflo(uv.y); accA[3] += aj * bfhi(uv.y);
    }
  }
#pragma unroll
  for (int off = 16; off; off >>= 1) lsum += __shfl_xor(lsum, off, 32);
  float invd = 1.0f / lsum;
  float4 b4 = *(const float4*)(bias + ls * VEC);
  float4 r;
  r.x = (accA[0] + accB[0]) * invd + b4.x;
  r.y = (accA[1] + accB[1]) * invd + b4.y;
  r.z = (accA[2] + accB[2]) * invd + b4.z;
  r.w = (accA[3] + accB[3]) * invd + b4.w;
  *(float4*)(outp + (size_t)i * F + ls * VEC) = r;
}

// ---------------- link predictor (one wave per pair, float2 per lane) ----------------
__global__ void predict_kernel(const float* __restrict__ h2, const int* __restrict__ mask,
                               const float* __restrict__ Wl, const float* __restrict__ bl,
                               float* __restrict__ out, int P) {
  int wid = (blockIdx.x * blockDim.x + threadIdx.x) >> 6;
  int lane = threadIdx.x & 63;
  if (wid >= P) return;
  int m0 = mask[wid * 2 + 0];
  int m1 = mask[wid * 2 + 1];
  float2 x0 = *(const float2*)(h2 + (size_t)m0 * FIN + lane * 2);
  float2 x1 = *(const float2*)(h2 + (size_t)m1 * FIN + lane * 2);
  float2 w0 = *(const float2*)(Wl + lane * 2);
  float2 w1 = *(const float2*)(Wl + FIN + lane * 2);
  float s = x0.x * w0.x + x0.y * w0.y + x1.x * w1.x + x1.y * w1.y;
#pragma unroll
  for (int off = 32; off; off >>= 1) s += __shfl_down(s, off);
  if (lane == 0) {
    float z = s + bl[0];
    out[wid] = 1.0f / (1.0f + expf(-z));
  }
}

extern "C" void kernel_launch(void* const* d_in, const int* in_sizes, int n_in,
                              void* d_out, int out_size, void* d_ws, size_t ws_size,
                              hipStream_t stream) {
  const float* features = (const float*)d_in[0];
  const int* edge_index = (const int*)d_in[1];
  const int* mask       = (const int*)d_in[2];
  const float* W1     = (const float*)d_in[3];
  const float* a_src1 = (const float*)d_in[4];
  const float* a_dst1 = (const float*)d_in[5];
  const float* b1     = (const float*)d_in[6];
  const float* W2     = (const float*)d_in[7];
  const float* a_src2 = (const float*)d_in[8];
  const float* a_dst2 = (const float*)d_in[9];
  const float* b2     = (const float*)d_in[10];
  const float* Wl     = (const float*)d_in[11];
  const float* bl     = (const float*)d_in[12];
  float* out = (float*)d_out;

  const int* src = edge_index;        // [E]
  const int* dst = edge_index + NE;   // [E]

  // ---- workspace layout ----
  char* ws = (char*)d_ws;
  size_t off = 0;
  auto alloc = [&](size_t bytes) {
    void* p = ws + off;
    off += (bytes + 255) & ~(size_t)255;
    return p;
  };
  unsigned short* h_buf = (unsigned short*)alloc((size_t)NN * HD * 2);   // h1/h2 bf16
  unsigned short* x2b   = (unsigned short*)alloc((size_t)NN * HD * 2);   // relu(out1) bf16
  float* out2    = (float*)alloc((size_t)NN * FIN * 4);                  // layer2 agg out fp32
  unsigned short* W1T = (unsigned short*)alloc((size_t)HD * FIN * 2);    // [256][128]
  unsigned short* W2T = (unsigned short*)alloc((size_t)FIN * HD * 2);    // [128][256]
  float* es_buf  = (float*)alloc((size_t)NN * 4);
  float* ed_buf  = (float*)alloc((size_t)NN * 4);
  int* deg       = (int*)alloc((size_t)NN * 4);
  int* incl      = (int*)alloc((size_t)NN * 4);
  int* bsum      = (int*)alloc(1024);
  int* row_ptr   = (int*)alloc((size_t)(NN + 1) * 4);
  int* cursor    = (int*)alloc((size_t)NN * 4);
  int* ssrc      = (int*)alloc((size_t)NE_TOT * 4);
  int* flags     = (int*)alloc((size_t)NN * 4);
  int* node_list = (int*)alloc((size_t)NN * 4);
  int* node_cnt  = (int*)alloc(256);
  (void)ws_size; (void)in_sizes; (void)n_in; (void)out_size;

  const int nblk_n256 = (NN + 255) / 256;          // 196
  const int nblk_gemm = (NN + 63) / 64;            // 782

  // ---- init + CSR build ----
  init_misc<<<nblk_n256, 256, 0, stream>>>(deg, flags, node_cnt, NN);
  hist_kernel<<<(NE + 255) / 256, 256, 0, stream>>>(dst, NE, deg);
  scan_phase1<<<nblk_n256, 256, 0, stream>>>(deg, incl, bsum, NN);
  scan_phase2<<<1, 256, 0, stream>>>(bsum, nblk_n256);
  scan_phase3<<<nblk_n256 + 1, 256, 0, stream>>>(deg, incl, bsum, row_ptr, cursor, NN, NE_TOT);
  scatter_kernel<<<(NE_TOT + 255) / 256, 256, 0, stream>>>(src, dst, NE, NN, cursor, ssrc);

  // ---- masked-node set + weights ----
  flag_kernel<<<(2 * NP + 255) / 256, 256, 0, stream>>>(mask, 2 * NP, flags);
  compact_kernel<<<nblk_n256, 256, 0, stream>>>(flags, node_list, node_cnt, NN);
  prep_weights<<<(2 * FIN * HD + 255) / 256, 256, 0, stream>>>(W1, W2, W1T, W2T);

  // ---- layer 1: h1 = X @ W1 (MFMA bf16) + fused es/ed (plain store) ----
  mfma_gemm<HD, FIN, false><<<nblk_gemm, 256, 0, stream>>>(
      (const void*)features, W1T, h_buf, a_src1, a_dst1, es_buf, ed_buf, NN);
  // fused softmax + aggregation (all nodes), one node per wave, bf16 out + relu
  fused_agg64<<<(NN + 3) / 4, 256, 0, stream>>>(
      row_ptr, ssrc, es_buf, ed_buf, h_buf, b1, x2b, NN);

  // ---- layer 2: h2 = x2 @ W2 (MFMA bf16) + fused es/ed ----
  mfma_gemm<FIN, HD, true><<<nblk_gemm, 256, 0, stream>>>(
      (const void*)x2b, W2T, h_buf, a_src2, a_dst2, es_buf, ed_buf, NN);
  // fused agg restricted to masked dst nodes, fp32 out
  fused_agg_l2<<<(2 * NP + 7) / 8, 256, 0, stream>>>(
      row_ptr, ssrc, es_buf, ed_buf, h_buf, b2, out2, node_list, node_cnt);

  // ---- link predictor ----
  predict_kernel<<<(NP * 64 + 255) / 256, 256, 0, stream>>>(out2, mask, Wl, bl, out, NP);
}

// Round 8
// 245.811 us; speedup vs baseline: 2.1432x; 1.0457x over previous
//
#include <hip/hip_runtime.h>
#include <hip/hip_bf16.h>
#include <math.h>

#define NN 50000      // nodes
#define NE 500000     // edges (before self loops)
#define NP 10000      // pairs
#define FIN 128
#define HD 256
#define NE_TOT (NE + NN)   // with self loops

typedef __attribute__((ext_vector_type(8))) short bf16x8;
typedef __attribute__((ext_vector_type(4))) float f32x4;
typedef __attribute__((ext_vector_type(2))) float f32x2;

// round-to-nearest-even fp32 -> bf16 bits
__device__ inline unsigned short f2bf(float f) {
  unsigned int u = __float_as_uint(f);
  unsigned int r = (u + 0x7fffu + ((u >> 16) & 1u)) >> 16;
  return (unsigned short)r;
}

__device__ inline float bflo(unsigned int u) { return __uint_as_float(u << 16); }
__device__ inline float bfhi(unsigned int u) { return __uint_as_float(u & 0xffff0000u); }

// fp8 e4m3 encode (HW, RNE): one float -> one byte
__device__ inline unsigned char f2fp8(float v) {
  int pk = __builtin_amdgcn_cvt_pk_fp8_f32(v, v, 0, false);
  return (unsigned char)(pk & 0xff);
}

// ---------------- merged init: deg=1 (self loop), flags=0, node_cnt=0 ----------------
__global__ void init_misc(int* __restrict__ deg, int* __restrict__ flags,
                          int* __restrict__ node_cnt, int n) {
  int i = blockIdx.x * 256 + threadIdx.x;
  if (i < n) { deg[i] = 1; flags[i] = 0; }
  if (i == 0) *node_cnt = 0;
}

// ---------------- merged weight transpose+convert (both layers) ----------------
__global__ void prep_weights(const float* __restrict__ W1, const float* __restrict__ W2,
                             unsigned short* __restrict__ W1T, unsigned short* __restrict__ W2T) {
  int idx = blockIdx.x * 256 + threadIdx.x;
  if (idx < FIN * HD) {
    int n = idx / FIN, k = idx - n * FIN;
    W1T[idx] = f2bf(W1[(size_t)k * HD + n]);
  } else if (idx < 2 * FIN * HD) {
    int id2 = idx - FIN * HD;
    int n = id2 / HD, k = id2 - n * HD;
    W2T[id2] = f2bf(W2[(size_t)k * FIN + n]);
  }
}

// ---------------- bf16 MFMA GEMM + fused es/ed epilogue (LDS reduce, plain store) ----------------
// C[M,BN] = A[M,KTOT] @ B[KTOT,BN]; BT is B^T bf16 [BN][KTOT].
// C stored fp8-e4m3 (C_FP8) or bf16. es/ed from fp32 accumulators (exact).
template <int BN, int KTOT, bool A_BF16, bool C_FP8>
__global__ __launch_bounds__(256)
void mfma_gemm(const void* __restrict__ Aptr, const unsigned short* __restrict__ BT,
               void* __restrict__ Cptr, const float* __restrict__ a_s,
               const float* __restrict__ a_d, float* __restrict__ es, float* __restrict__ ed,
               int M) {
  constexpr int LDK = 72;
  constexpr int CN = BN / 2;   // cols per wave
  constexpr int NT = CN / 16;  // 16x16 col tiles per wave
  __shared__ unsigned short As[64][LDK];
  __shared__ unsigned short Bs[BN][LDK];
  __shared__ float esl[64][2];
  __shared__ float edl[64][2];
  const int tid = threadIdx.x;
  const int wave = tid >> 6;
  const int lane = tid & 63;
  const int quad = lane >> 4;
  const int l16 = lane & 15;
  const int wrow = wave >> 1;  // 0..1
  const int wcol = wave & 1;   // 0..1
  const int row0 = blockIdx.x * 64;

  f32x4 acc[2][NT] = {};

  for (int k0 = 0; k0 < KTOT; k0 += 64) {
#pragma unroll
    for (int p = 0; p < 4; p++) {
      int m = p * 16 + (tid >> 4);
      int k4 = (tid & 15) * 4;
      int gr = row0 + m;
      uint2 pk = make_uint2(0u, 0u);
      if (gr < M) {
        if (A_BF16) {
          pk = *(const uint2*)((const unsigned short*)Aptr + (size_t)gr * KTOT + k0 + k4);
        } else {
          float4 v = *(const float4*)((const float*)Aptr + (size_t)gr * KTOT + k0 + k4);
          pk.x = (unsigned int)f2bf(v.x) | ((unsigned int)f2bf(v.y) << 16);
          pk.y = (unsigned int)f2bf(v.z) | ((unsigned int)f2bf(v.w) << 16);
        }
      }
      *(uint2*)&As[m][k4] = pk;
    }
#pragma unroll
    for (int p = 0; p < BN / 32; p++) {
      int n = p * 32 + (tid >> 3);
      int k8 = (tid & 7) * 8;
      *(uint4*)&Bs[n][k8] = *(const uint4*)(BT + (size_t)n * KTOT + k0 + k8);
    }
    __syncthreads();
#pragma unroll
    for (int ks = 0; ks < 2; ks++) {
      bf16x8 afrag[2];
#pragma unroll
      for (int rt = 0; rt < 2; rt++)
        afrag[rt] = *(const bf16x8*)&As[wrow * 32 + rt * 16 + l16][ks * 32 + quad * 8];
#pragma unroll
      for (int ct = 0; ct < NT; ct++) {
        bf16x8 bfrag = *(const bf16x8*)&Bs[wcol * CN + ct * 16 + l16][ks * 32 + quad * 8];
#pragma unroll
        for (int rt = 0; rt < 2; rt++)
          acc[rt][ct] = __builtin_amdgcn_mfma_f32_16x16x32_bf16(afrag[rt], bfrag, acc[rt][ct], 0, 0, 0);
      }
    }
    __syncthreads();
  }

  float asv[NT], adv[NT];
#pragma unroll
  for (int ct = 0; ct < NT; ct++) {
    asv[ct] = a_s[wcol * CN + ct * 16 + l16];
    adv[ct] = a_d[wcol * CN + ct * 16 + l16];
  }
#pragma unroll
  for (int rt = 0; rt < 2; rt++) {
#pragma unroll
    for (int r = 0; r < 4; r++) {
      int lrow = wrow * 32 + rt * 16 + quad * 4 + r;
      int grow = row0 + lrow;
      bool ok = (grow < M);
      float ps = 0.f, pd = 0.f;
#pragma unroll
      for (int ct = 0; ct < NT; ct++) {
        float v = acc[rt][ct][r];
        ps += v * asv[ct];
        pd += v * adv[ct];
        if (ok) {
          size_t cidx = (size_t)grow * BN + wcol * CN + ct * 16 + l16;
          if (C_FP8) ((unsigned char*)Cptr)[cidx] = f2fp8(v);
          else       ((unsigned short*)Cptr)[cidx] = f2bf(v);
        }
      }
#pragma unroll
      for (int off = 1; off < 16; off <<= 1) {
        ps += __shfl_xor(ps, off, 16);
        pd += __shfl_xor(pd, off, 16);
      }
      if (l16 == 0) {
        esl[lrow][wcol] = ps;
        edl[lrow][wcol] = pd;
      }
    }
  }
  __syncthreads();
  if (tid < 64) {
    int grow = row0 + tid;
    if (grow < M) {
      es[grow] = esl[tid][0] + esl[tid][1];
      ed[grow] = edl[tid][0] + edl[tid][1];
    }
  }
}

// ---------------- CSR build ----------------
__global__ void hist_kernel(const int* __restrict__ dst, int E, int* __restrict__ deg) {
  int e = blockIdx.x * blockDim.x + threadIdx.x;
  if (e < E) atomicAdd(&deg[dst[e]], 1);
}

__global__ void scan_phase1(const int* __restrict__ deg, int* __restrict__ incl,
                            int* __restrict__ bsum, int n) {
  __shared__ int tmp[256];
  int i = blockIdx.x * 256 + threadIdx.x;
  int v = (i < n) ? deg[i] : 0;
  tmp[threadIdx.x] = v;
  __syncthreads();
  for (int off = 1; off < 256; off <<= 1) {
    int t = (threadIdx.x >= off) ? tmp[threadIdx.x - off] : 0;
    __syncthreads();
    tmp[threadIdx.x] += t;
    __syncthreads();
  }
  if (i < n) incl[i] = tmp[threadIdx.x];
  if (threadIdx.x == 255) bsum[blockIdx.x] = tmp[255];
}

__global__ void scan_phase2(int* __restrict__ bsum, int nb) {
  __shared__ int tmp[256];
  int v = (threadIdx.x < nb) ? bsum[threadIdx.x] : 0;
  tmp[threadIdx.x] = v;
  __syncthreads();
  for (int off = 1; off < 256; off <<= 1) {
    int t = (threadIdx.x >= off) ? tmp[threadIdx.x - off] : 0;
    __syncthreads();
    tmp[threadIdx.x] += t;
    __syncthreads();
  }
  if (threadIdx.x < nb) bsum[threadIdx.x] = tmp[threadIdx.x] - v;  // exclusive
}

__global__ void scan_phase3(const int* __restrict__ deg, const int* __restrict__ incl,
                            const int* __restrict__ bsum, int* __restrict__ row_ptr,
                            int* __restrict__ cursor, int n, int total) {
  int i = blockIdx.x * 256 + threadIdx.x;
  if (i < n) {
    int excl = incl[i] - deg[i] + bsum[blockIdx.x];
    row_ptr[i] = excl;
    cursor[i] = excl;
  }
  if (i == n) row_ptr[n] = total;
}

__global__ void scatter_kernel(const int* __restrict__ src, const int* __restrict__ dst,
                               int E, int N, int* __restrict__ cursor, int* __restrict__ ssrc) {
  int e = blockIdx.x * blockDim.x + threadIdx.x;
  if (e < E) {
    int pos = atomicAdd(&cursor[dst[e]], 1);
    ssrc[pos] = src[e];
  } else if (e < E + N) {
    int i = e - E;
    int pos = atomicAdd(&cursor[i], 1);
    ssrc[pos] = i;
  }
}

// ---------------- mask node set: flag + compact ----------------
__global__ void flag_kernel(const int* __restrict__ mask, int n2, int* __restrict__ flags) {
  int t = blockIdx.x * 256 + threadIdx.x;
  if (t < n2) flags[mask[t]] = 1;
}

__global__ void compact_kernel(const int* __restrict__ flags, int* __restrict__ list,
                               int* __restrict__ cnt, int n) {
  int i = blockIdx.x * 256 + threadIdx.x;
  if (i < n && flags[i]) {
    int p = atomicAdd(cnt, 1);
    list[p] = i;
  }
}

// ---------------- fused softmax+agg, one node per 64-lane wave, fp8 h rows (F=256) ----------------
// Per edge: (src, weight) broadcast via readlane -> SGPR; row load dword (4 fp8/lane).
__global__ __launch_bounds__(256)
void fused_agg64(const int* __restrict__ row_ptr, const int* __restrict__ ssrc,
                 const float* __restrict__ es, const float* __restrict__ ed,
                 const unsigned char* __restrict__ h, const float* __restrict__ bias,
                 unsigned short* __restrict__ outp, int n) {
  int i = blockIdx.x * 4 + (threadIdx.x >> 6);
  int lane = threadIdx.x & 63;
  if (i >= n) return;
  int s = row_ptr[i], e = row_ptr[i + 1];
  int deg = e - s;
  float edv = ed[i];

  // phase 1: chunk-0 logits cached; extra chunks (deg>64: ~never) for max
  int msrc0 = 0;
  float logit0 = -1e30f;
  if (lane < deg) {
    msrc0 = ssrc[s + lane];
    float t = es[msrc0] + edv;
    logit0 = (t > 0.f) ? t : 0.2f * t;
  }
  float mloc = logit0;
  for (int p0 = s + 64; p0 < e; p0 += 64) {
    int p = p0 + lane;
    if (p < e) {
      int ms = ssrc[p];
      float t = es[ms] + edv;
      float lg = (t > 0.f) ? t : 0.2f * t;
      mloc = fmaxf(mloc, lg);
    }
  }
#pragma unroll
  for (int off = 32; off; off >>= 1) mloc = fmaxf(mloc, __shfl_xor(mloc, off, 64));

  // phase 2: exp + accumulate (uniform readlane broadcast, 8-edge load batches)
  float pv = (lane < deg) ? __expf(logit0 - mloc) : 0.f;
  float lsum = pv;
  unsigned int pvu = __float_as_uint(pv);
  float acc0 = 0.f, acc1 = 0.f, acc2 = 0.f, acc3 = 0.f;
  const unsigned char* hb = h + lane * 4;  // 4 fp8 per lane, 256 B per row-load
  int cnt0 = min(deg, 64);
  int j = 0;
  for (; j + 8 <= cnt0; j += 8) {
    unsigned int r[8];
    float w[8];
#pragma unroll
    for (int u = 0; u < 8; u++) {
      int sj = __builtin_amdgcn_readlane(msrc0, j + u);
      w[u] = __uint_as_float(__builtin_amdgcn_readlane(pvu, j + u));
      r[u] = *(const unsigned int*)(hb + (size_t)sj * HD);
    }
#pragma unroll
    for (int u = 0; u < 8; u++) {
      f32x2 lo = __builtin_amdgcn_cvt_pk_f32_fp8(r[u], false);
      f32x2 hi = __builtin_amdgcn_cvt_pk_f32_fp8(r[u], true);
      acc0 += w[u] * lo.x;
      acc1 += w[u] * lo.y;
      acc2 += w[u] * hi.x;
      acc3 += w[u] * hi.y;
    }
  }
  for (; j < cnt0; j++) {
    int sj = __builtin_amdgcn_readlane(msrc0, j);
    float wj = __uint_as_float(__builtin_amdgcn_readlane(pvu, j));
    unsigned int rv = *(const unsigned int*)(hb + (size_t)sj * HD);
    f32x2 lo = __builtin_amdgcn_cvt_pk_f32_fp8(rv, false);
    f32x2 hi = __builtin_amdgcn_cvt_pk_f32_fp8(rv, true);
    acc0 += wj * lo.x;
    acc1 += wj * lo.y;
    acc2 += wj * hi.x;
    acc3 += wj * hi.y;
  }
  // rare: deg > 64
  for (int p0 = s + 64; p0 < e; p0 += 64) {
    int p = p0 + lane;
    int ms = 0;
    float lg = -1e30f;
    if (p < e) {
      ms = ssrc[p];
      float t = es[ms] + edv;
      lg = (t > 0.f) ? t : 0.2f * t;
    }
    float pvc = (p < e) ? __expf(lg - mloc) : 0.f;
    lsum += pvc;
    unsigned int pvcu = __float_as_uint(pvc);
    int cnt = min(64, e - p0);
    for (int jj = 0; jj < cnt; jj++) {
      int sj = __builtin_amdgcn_readlane(ms, jj);
      float wj = __uint_as_float(__builtin_amdgcn_readlane(pvcu, jj));
      unsigned int rv = *(const unsigned int*)(hb + (size_t)sj * HD);
      f32x2 lo = __builtin_amdgcn_cvt_pk_f32_fp8(rv, false);
      f32x2 hi = __builtin_amdgcn_cvt_pk_f32_fp8(rv, true);
      acc0 += wj * lo.x;
      acc1 += wj * lo.y;
      acc2 += wj * hi.x;
      acc3 += wj * hi.y;
    }
  }
#pragma unroll
  for (int off = 32; off; off >>= 1) lsum += __shfl_xor(lsum, off, 64);
  float invd = 1.0f / lsum;
  float4 b4 = *(const float4*)(bias + lane * 4);
  float r0 = fmaxf(acc0 * invd + b4.x, 0.f);   // relu (layer 1 only)
  float r1 = fmaxf(acc1 * invd + b4.y, 0.f);
  float r2 = fmaxf(acc2 * invd + b4.z, 0.f);
  float r3 = fmaxf(acc3 * invd + b4.w, 0.f);
  uint2 pk;
  pk.x = (unsigned int)f2bf(r0) | ((unsigned int)f2bf(r1) << 16);
  pk.y = (unsigned int)f2bf(r2) | ((unsigned int)f2bf(r3) << 16);
  *(uint2*)(outp + (size_t)i * HD + lane * 4) = pk;
}

// ---------------- layer-2 fused agg (32 lanes/node, masked list, bf16 h2, fp32 out) ----------------
__global__ __launch_bounds__(256)
void fused_agg_l2(const int* __restrict__ row_ptr, const int* __restrict__ ssrc,
                  const float* __restrict__ es, const float* __restrict__ ed,
                  const unsigned short* __restrict__ h, const float* __restrict__ bias,
                  float* __restrict__ outp, const int* __restrict__ node_list,
                  const int* __restrict__ node_cnt) {
  constexpr int F = FIN;
  constexpr int VEC = 4;
  int idx = blockIdx.x * 8 + (threadIdx.x >> 5);
  int ls = threadIdx.x & 31;
  if (idx >= *node_cnt) return;
  int i = node_list[idx];
  int s = row_ptr[i], e = row_ptr[i + 1];
  float edv = ed[i];

  int msrc0 = 0;
  float logit0 = -1e30f;
  {
    int p = s + ls;
    if (p < e) {
      msrc0 = ssrc[p];
      float t = es[msrc0] + edv;
      logit0 = (t > 0.f) ? t : 0.2f * t;
    }
  }
  float M = logit0;
  for (int p0 = s + 32; p0 < e; p0 += 32) {
    int p = p0 + ls;
    if (p < e) {
      int ms = ssrc[p];
      float t = es[ms] + edv;
      float lg = (t > 0.f) ? t : 0.2f * t;
      M = fmaxf(M, lg);
    }
  }
#pragma unroll
  for (int off = 16; off; off >>= 1) M = fmaxf(M, __shfl_xor(M, off, 32));

  float accA[VEC] = {}, accB[VEC] = {};
  float lsum = 0.f;
  const unsigned short* hb = h + ls * VEC;
  for (int p0 = s; p0 < e; p0 += 32) {
    int msrc;
    float logit;
    if (p0 == s) {
      msrc = msrc0;
      logit = logit0;
    } else {
      int p = p0 + ls;
      msrc = 0;
      logit = -1e30f;
      if (p < e) {
        msrc = ssrc[p];
        float t = es[msrc] + edv;
        logit = (t > 0.f) ? t : 0.2f * t;
      }
    }
    float pv = __expf(logit - M);
    lsum += pv;
    int cnt = min(32, e - p0);
    int j = 0;
    for (; j + 4 <= cnt; j += 4) {
      int s0 = __shfl(msrc, j + 0, 32), s1 = __shfl(msrc, j + 1, 32);
      int s2 = __shfl(msrc, j + 2, 32), s3 = __shfl(msrc, j + 3, 32);
      float a0 = __shfl(pv, j + 0, 32), a1 = __shfl(pv, j + 1, 32);
      float a2 = __shfl(pv, j + 2, 32), a3 = __shfl(pv, j + 3, 32);
      uint2 u0 = *(const uint2*)(hb + (size_t)s0 * F);
      uint2 u1 = *(const uint2*)(hb + (size_t)s1 * F);
      uint2 u2 = *(const uint2*)(hb + (size_t)s2 * F);
      uint2 u3 = *(const uint2*)(hb + (size_t)s3 * F);
      accA[0] += a0 * bflo(u0.x); accA[1] += a0 * bfhi(u0.x);
      accA[2] += a0 * bflo(u0.y); accA[3] += a0 * bfhi(u0.y);
      accB[0] += a1 * bflo(u1.x); accB[1] += a1 * bfhi(u1.x);
      accB[2] += a1 * bflo(u1.y); accB[3] += a1 * bfhi(u1.y);
      accA[0] += a2 * bflo(u2.x); accA[1] += a2 * bfhi(u2.x);
      accA[2] += a2 * bflo(u2.y); accA[3] += a2 * bfhi(u2.y);
      accB[0] += a3 * bflo(u3.x); accB[1] += a3 * bfhi(u3.x);
      accB[2] += a3 * bflo(u3.y); accB[3] += a3 * bfhi(u3.y);
    }
    for (; j < cnt; j++) {
      int sj = __shfl(msrc, j, 32);
      float aj = __shfl(pv, j, 32);
      uint2 uv = *(const uint2*)(hb + (size_t)sj * F);
      accA[0] += aj * bflo(uv.x); accA[1] += aj * bfhi(uv.x);
      accA[2] += aj * bflo(uv.y); accA[3] += aj * bfhi(uv.y);
    }
  }
#pragma unroll
  for (int off = 16; off; off >>= 1) lsum += __shfl_xor(lsum, off, 32);
  float invd = 1.0f / lsum;
  float4 b4 = *(const float4*)(bias + ls * VEC);
  float4 r;
  r.x = (accA[0] + accB[0]) * invd + b4.x;
  r.y = (accA[1] + accB[1]) * invd + b4.y;
  r.z = (accA[2] + accB[2]) * invd + b4.z;
  r.w = (accA[3] + accB[3]) * invd + b4.w;
  *(float4*)(outp + (size_t)i * F + ls * VEC) = r;
}

// ---------------- link predictor (one wave per pair, float2 per lane) ----------------
__global__ void predict_kernel(const float* __restrict__ h2, const int* __restrict__ mask,
                               const float* __restrict__ Wl, const float* __restrict__ bl,
                               float* __restrict__ out, int P) {
  int wid = (blockIdx.x * blockDim.x + threadIdx.x) >> 6;
  int lane = threadIdx.x & 63;
  if (wid >= P) return;
  int m0 = mask[wid * 2 + 0];
  int m1 = mask[wid * 2 + 1];
  float2 x0 = *(const float2*)(h2 + (size_t)m0 * FIN + lane * 2);
  float2 x1 = *(const float2*)(h2 + (size_t)m1 * FIN + lane * 2);
  float2 w0 = *(const float2*)(Wl + lane * 2);
  float2 w1 = *(const float2*)(Wl + FIN + lane * 2);
  float s = x0.x * w0.x + x0.y * w0.y + x1.x * w1.x + x1.y * w1.y;
#pragma unroll
  for (int off = 32; off; off >>= 1) s += __shfl_down(s, off);
  if (lane == 0) {
    float z = s + bl[0];
    out[wid] = 1.0f / (1.0f + expf(-z));
  }
}

extern "C" void kernel_launch(void* const* d_in, const int* in_sizes, int n_in,
                              void* d_out, int out_size, void* d_ws, size_t ws_size,
                              hipStream_t stream) {
  const float* features = (const float*)d_in[0];
  const int* edge_index = (const int*)d_in[1];
  const int* mask       = (const int*)d_in[2];
  const float* W1     = (const float*)d_in[3];
  const float* a_src1 = (const float*)d_in[4];
  const float* a_dst1 = (const float*)d_in[5];
  const float* b1     = (const float*)d_in[6];
  const float* W2     = (const float*)d_in[7];
  const float* a_src2 = (const float*)d_in[8];
  const float* a_dst2 = (const float*)d_in[9];
  const float* b2     = (const float*)d_in[10];
  const float* Wl     = (const float*)d_in[11];
  const float* bl     = (const float*)d_in[12];
  float* out = (float*)d_out;

  const int* src = edge_index;        // [E]
  const int* dst = edge_index + NE;   // [E]

  // ---- workspace layout ----
  char* ws = (char*)d_ws;
  size_t off = 0;
  auto alloc = [&](size_t bytes) {
    void* p = ws + off;
    off += (bytes + 255) & ~(size_t)255;
    return p;
  };
  unsigned char* h1q = (unsigned char*)alloc((size_t)NN * HD);            // h1 fp8 (gather rows)
  unsigned short* h2b = (unsigned short*)alloc((size_t)NN * FIN * 2);     // h2 bf16
  unsigned short* x2b = (unsigned short*)alloc((size_t)NN * HD * 2);      // relu(out1) bf16
  float* out2    = (float*)alloc((size_t)NN * FIN * 4);                   // layer2 agg out fp32
  unsigned short* W1T = (unsigned short*)alloc((size_t)HD * FIN * 2);     // [256][128]
  unsigned short* W2T = (unsigned short*)alloc((size_t)FIN * HD * 2);     // [128][256]
  float* es_buf  = (float*)alloc((size_t)NN * 4);
  float* ed_buf  = (float*)alloc((size_t)NN * 4);
  int* deg       = (int*)alloc((size_t)NN * 4);
  int* incl      = (int*)alloc((size_t)NN * 4);
  int* bsum      = (int*)alloc(1024);
  int* row_ptr   = (int*)alloc((size_t)(NN + 1) * 4);
  int* cursor    = (int*)alloc((size_t)NN * 4);
  int* ssrc      = (int*)alloc((size_t)NE_TOT * 4);
  int* flags     = (int*)alloc((size_t)NN * 4);
  int* node_list = (int*)alloc((size_t)NN * 4);
  int* node_cnt  = (int*)alloc(256);
  (void)ws_size; (void)in_sizes; (void)n_in; (void)out_size;

  const int nblk_n256 = (NN + 255) / 256;          // 196
  const int nblk_gemm = (NN + 63) / 64;            // 782

  // ---- init + CSR build ----
  init_misc<<<nblk_n256, 256, 0, stream>>>(deg, flags, node_cnt, NN);
  hist_kernel<<<(NE + 255) / 256, 256, 0, stream>>>(dst, NE, deg);
  scan_phase1<<<nblk_n256, 256, 0, stream>>>(deg, incl, bsum, NN);
  scan_phase2<<<1, 256, 0, stream>>>(bsum, nblk_n256);
  scan_phase3<<<nblk_n256 + 1, 256, 0, stream>>>(deg, incl, bsum, row_ptr, cursor, NN, NE_TOT);
  scatter_kernel<<<(NE_TOT + 255) / 256, 256, 0, stream>>>(src, dst, NE, NN, cursor, ssrc);

  // ---- masked-node set + weights ----
  flag_kernel<<<(2 * NP + 255) / 256, 256, 0, stream>>>(mask, 2 * NP, flags);
  compact_kernel<<<nblk_n256, 256, 0, stream>>>(flags, node_list, node_cnt, NN);
  prep_weights<<<(2 * FIN * HD + 255) / 256, 256, 0, stream>>>(W1, W2, W1T, W2T);

  // ---- layer 1: h1 = X @ W1 (MFMA bf16, C in fp8) + fused es/ed ----
  mfma_gemm<HD, FIN, false, true><<<nblk_gemm, 256, 0, stream>>>(
      (const void*)features, W1T, (void*)h1q, a_src1, a_dst1, es_buf, ed_buf, NN);
  // fused softmax + aggregation (all nodes), one node per wave, fp8 gather, bf16 out + relu
  fused_agg64<<<(NN + 3) / 4, 256, 0, stream>>>(
      row_ptr, ssrc, es_buf, ed_buf, h1q, b1, x2b, NN);

  // ---- layer 2: h2 = x2 @ W2 (MFMA bf16, C in bf16) + fused es/ed ----
  mfma_gemm<FIN, HD, true, false><<<nblk_gemm, 256, 0, stream>>>(
      (const void*)x2b, W2T, (void*)h2b, a_src2, a_dst2, es_buf, ed_buf, NN);
  // fused agg restricted to masked dst nodes, fp32 out
  fused_agg_l2<<<(2 * NP + 7) / 8, 256, 0, stream>>>(
      row_ptr, ssrc, es_buf, ed_buf, h2b, b2, out2, node_list, node_cnt);

  // ---- link predictor ----
  predict_kernel<<<(NP * 64 + 255) / 256, 256, 0, stream>>>(out2, mask, Wl, bl, out, NP);
}